// Round 2
// baseline (3998.158 us; speedup 1.0000x reference)
//
#include <hip/hip_runtime.h>
#include <hip/hip_bf16.h>
#include <math.h>

// ---------------------------------------------------------------------------
// Swin/SAM-style block: LN1 -> window attention (rel-pos) -> +x -> LN2 -> MLP -> +
// Baseline round: SIMT fp32-accumulate GEMMs, bf16 intermediates.
// R1 fix: workspace aliasing (rel tables overlapped qkv tail -> NaN).
// ---------------------------------------------------------------------------

#define DIMC 768
#define HEADS 12
#define HDIM 64
#define WIN 14
#define NTOK 196          // 14*14
#define NWIN 50           // 2 images * 5*5 windows
#define MROWS 9800        // NWIN * NTOK
#define YROWS 8192        // 2*64*64
#define MLP_HID 3072

__device__ __forceinline__ float bf2f(unsigned short u) {
    return __uint_as_float(((unsigned)u) << 16);
}
__device__ __forceinline__ unsigned short f2bf(float f) {
    unsigned u = __float_as_uint(f);
    unsigned r = (u + 0x7fffu + ((u >> 16) & 1u)) >> 16;   // round-nearest-even
    return (unsigned short)r;
}

// ---------------- LN1 + window partition (zeros in padding) ----------------
__global__ __launch_bounds__(256) void ln1_win_kernel(
        const float* __restrict__ x, const float* __restrict__ g,
        const float* __restrict__ b, unsigned short* __restrict__ h1) {
    int tid = threadIdx.x;
    int row = blockIdx.x * 4 + (tid >> 6);
    int lane = tid & 63;
    if (row >= MROWS) return;
    int w = row / NTOK, t = row % NTOK;
    int bi = w / 25, wr = w % 25;
    int gy = (wr / 5) * WIN + t / WIN;
    int gx = (wr % 5) * WIN + t % WIN;
    unsigned short* out = h1 + (size_t)row * DIMC;
    if (gy >= 64 || gx >= 64) {           // pad token: reference pads AFTER LN
        #pragma unroll
        for (int j = 0; j < 12; j++) out[lane + 64 * j] = 0;
        return;
    }
    const float* xr = x + ((size_t)((bi * 64 + gy) * 64 + gx)) * DIMC;
    float v[12], s = 0.f;
    #pragma unroll
    for (int j = 0; j < 12; j++) { v[j] = xr[lane + 64 * j]; s += v[j]; }
    #pragma unroll
    for (int o = 32; o > 0; o >>= 1) s += __shfl_xor(s, o);
    float mean = s * (1.f / 768.f);
    float q = 0.f;
    #pragma unroll
    for (int j = 0; j < 12; j++) { float d = v[j] - mean; q += d * d; }
    #pragma unroll
    for (int o = 32; o > 0; o >>= 1) q += __shfl_xor(q, o);
    float inv = rsqrtf(q * (1.f / 768.f) + 1e-6f);
    #pragma unroll
    for (int j = 0; j < 12; j++) {
        int c = lane + 64 * j;
        out[c] = f2bf((v[j] - mean) * inv * g[c] + b[c]);
    }
}

// ---------------- LN2 (plain rows) ----------------
__global__ __launch_bounds__(256) void ln2_kernel(
        const float* __restrict__ y, const float* __restrict__ g,
        const float* __restrict__ b, unsigned short* __restrict__ h2) {
    int tid = threadIdx.x;
    int row = blockIdx.x * 4 + (tid >> 6);
    int lane = tid & 63;
    const float* xr = y + (size_t)row * DIMC;
    float v[12], s = 0.f;
    #pragma unroll
    for (int j = 0; j < 12; j++) { v[j] = xr[lane + 64 * j]; s += v[j]; }
    #pragma unroll
    for (int o = 32; o > 0; o >>= 1) s += __shfl_xor(s, o);
    float mean = s * (1.f / 768.f);
    float q = 0.f;
    #pragma unroll
    for (int j = 0; j < 12; j++) { float d = v[j] - mean; q += d * d; }
    #pragma unroll
    for (int o = 32; o > 0; o >>= 1) q += __shfl_xor(q, o);
    float inv = rsqrtf(q * (1.f / 768.f) + 1e-6f);
    unsigned short* out = h2 + (size_t)row * DIMC;
    #pragma unroll
    for (int j = 0; j < 12; j++) {
        int c = lane + 64 * j;
        out[c] = f2bf((v[j] - mean) * inv * g[c] + b[c]);
    }
}

// ---------------- rel_h / rel_w tables: relh[bh, i, kh] = q[i,:] . rel_pos[iy-kh+13,:]
__global__ __launch_bounds__(256) void rel_kernel(
        const unsigned short* __restrict__ qkv,
        const float* __restrict__ relph, const float* __restrict__ relpw,
        float* __restrict__ outh, float* __restrict__ outw) {
    __shared__ unsigned short qs[NTOK * 66];
    int tid = threadIdx.x;
    int w = blockIdx.x / HEADS, head = blockIdx.x % HEADS;
    size_t base = (size_t)w * NTOK * 2304 + head * HDIM;   // q slice
    for (int e = tid; e < NTOK * 64; e += 256) {
        int t = e >> 6, d = e & 63;
        qs[t * 66 + d] = qkv[base + (size_t)t * 2304 + d];
    }
    __syncthreads();
    size_t obase = (size_t)blockIdx.x * (NTOK * WIN);
    for (int e = tid; e < 2 * NTOK * WIN; e += 256) {
        int which = e >= NTOK * WIN;
        int r = which ? e - NTOK * WIN : e;
        int i = r / WIN, kk = r % WIN;
        int pos = which ? (i % WIN) : (i / WIN);
        const float* tab = (which ? relpw : relph) + (size_t)(pos - kk + WIN - 1) * HDIM;
        const unsigned short* qrow = qs + i * 66;
        float s = 0.f;
        #pragma unroll
        for (int c = 0; c < 64; c++) s += bf2f(qrow[c]) * tab[c];
        (which ? outw : outh)[obase + r] = s;
    }
}

// ---------------- attention: one block per (window, head) ----------------
__global__ __launch_bounds__(256) void attn_kernel(
        const unsigned short* __restrict__ qkv,
        const float* __restrict__ relh_g, const float* __restrict__ relw_g,
        unsigned short* __restrict__ out) {
    __shared__ unsigned short ks[NTOK * 66];
    __shared__ unsigned short vs[NTOK * 66];
    int tid = threadIdx.x;
    int bh = blockIdx.x;
    int w = bh / HEADS, head = bh % HEADS;
    size_t base = (size_t)w * NTOK * 2304 + head * HDIM;
    for (int e = tid; e < NTOK * 64; e += 256) {
        int t = e >> 6, d = e & 63;
        size_t ga = base + (size_t)t * 2304 + d;
        ks[t * 66 + d] = qkv[ga + 768];
        vs[t * 66 + d] = qkv[ga + 1536];
    }
    __syncthreads();
    const float* rh_b = relh_g + (size_t)bh * (NTOK * WIN);
    const float* rw_b = relw_g + (size_t)bh * (NTOK * WIN);
    int wave = tid >> 6, lane = tid & 63;
    int j1 = lane, j2 = lane + 64, j3 = lane + 128, j4 = lane + 192;
    int jh1 = j1 / WIN, jw1 = j1 % WIN;
    int jh2 = j2 / WIN, jw2 = j2 % WIN;
    int jh3 = j3 / WIN, jw3 = j3 % WIN;
    bool val4 = j4 < NTOK;
    int jh4 = val4 ? j4 / WIN : 0, jw4 = val4 ? j4 % WIN : 0;

    for (int i = wave; i < NTOK; i += 4) {
        const unsigned short* qrow = qkv + base + (size_t)i * 2304;  // L1-resident
        float a1 = 0.f, a2 = 0.f, a3 = 0.f, a4 = 0.f;
        #pragma unroll 8
        for (int c = 0; c < 64; c++) {
            float qv = bf2f(qrow[c]);
            a1 += qv * bf2f(ks[j1 * 66 + c]);
            a2 += qv * bf2f(ks[j2 * 66 + c]);
            a3 += qv * bf2f(ks[j3 * 66 + c]);
            if (val4) a4 += qv * bf2f(ks[j4 * 66 + c]);
        }
        const float* rh = rh_b + i * WIN;
        const float* rw = rw_b + i * WIN;
        float s1 = a1 * 0.125f + rh[jh1] + rw[jw1];
        float s2 = a2 * 0.125f + rh[jh2] + rw[jw2];
        float s3 = a3 * 0.125f + rh[jh3] + rw[jw3];
        float s4 = val4 ? (a4 * 0.125f + rh[jh4] + rw[jw4]) : -1e30f;
        float m = fmaxf(fmaxf(s1, s2), fmaxf(s3, s4));
        #pragma unroll
        for (int o = 32; o > 0; o >>= 1) m = fmaxf(m, __shfl_xor(m, o));
        float p1 = __expf(s1 - m), p2 = __expf(s2 - m), p3 = __expf(s3 - m);
        float p4 = val4 ? __expf(s4 - m) : 0.f;
        float sum = p1 + p2 + p3 + p4;
        #pragma unroll
        for (int o = 32; o > 0; o >>= 1) sum += __shfl_xor(sum, o);
        float inv = 1.f / sum;
        float oacc = 0.f;
        for (int jl = 0; jl < 64; jl++) oacc += __shfl(p1, jl) * bf2f(vs[jl * 66 + lane]);
        for (int jl = 0; jl < 64; jl++) oacc += __shfl(p2, jl) * bf2f(vs[(64 + jl) * 66 + lane]);
        for (int jl = 0; jl < 64; jl++) oacc += __shfl(p3, jl) * bf2f(vs[(128 + jl) * 66 + lane]);
        for (int jl = 0; jl < 4;  jl++) oacc += __shfl(p4, jl) * bf2f(vs[(192 + jl) * 66 + lane]);
        // out layout: (window, token, head, hd) == (Bw, N, DIM)
        out[((size_t)(w * NTOK + i) * HEADS + head) * HDIM + lane] = f2bf(oacc * inv);
    }
}

// ---------------- generic GEMM: C = A(bf16, MxK) @ B(f32, KxN) + bias, epilogues
// EPI 0: store bf16       EPI 1: gelu(exact) -> bf16
// EPI 2: proj residual: window-unpartition row, C = x + v (f32)
// EPI 3: fc2 residual:  C = resid + v (f32)
template <int EPI>
__global__ __launch_bounds__(256) void gemm_kernel(
        const unsigned short* __restrict__ A, const float* __restrict__ B,
        const float* __restrict__ bias, void* __restrict__ Cout,
        const float* __restrict__ resid, int M, int Nn, int K) {
    __shared__ float As[16][65];
    __shared__ float Bs[16][64];
    int tid = threadIdx.x;
    int bn = blockIdx.x << 6, bm = blockIdx.y << 6;
    int tx = tid & 15, ty = tid >> 4;
    float acc[4][4] = {{0.f}};
    int am = tid >> 2, ak = (tid & 3) << 2;
    for (int k0 = 0; k0 < K; k0 += 16) {
        int row = bm + am;
        if (row < M) {
            const ushort4 a4 = *reinterpret_cast<const ushort4*>(A + (size_t)row * K + k0 + ak);
            As[ak + 0][am] = bf2f(a4.x);
            As[ak + 1][am] = bf2f(a4.y);
            As[ak + 2][am] = bf2f(a4.z);
            As[ak + 3][am] = bf2f(a4.w);
        } else {
            As[ak + 0][am] = 0.f; As[ak + 1][am] = 0.f;
            As[ak + 2][am] = 0.f; As[ak + 3][am] = 0.f;
        }
        #pragma unroll
        for (int r = 0; r < 4; r++) {
            int e = tid + (r << 8);
            Bs[e >> 6][e & 63] = B[(size_t)(k0 + (e >> 6)) * Nn + bn + (e & 63)];
        }
        __syncthreads();
        #pragma unroll
        for (int kk = 0; kk < 16; kk++) {
            float av[4], bv[4];
            #pragma unroll
            for (int i = 0; i < 4; i++) av[i] = As[kk][(ty << 2) + i];
            #pragma unroll
            for (int j = 0; j < 4; j++) bv[j] = Bs[kk][(tx << 2) + j];
            #pragma unroll
            for (int i = 0; i < 4; i++)
                #pragma unroll
                for (int j = 0; j < 4; j++) acc[i][j] += av[i] * bv[j];
        }
        __syncthreads();
    }
    #pragma unroll
    for (int i = 0; i < 4; i++) {
        int row = bm + (ty << 2) + i;
        if (row >= M) continue;
        if (EPI == 2) {
            int w = row / NTOK, t = row % NTOK;
            int bi = w / 25, wr = w % 25;
            int gy = (wr / 5) * WIN + t / WIN;
            int gx = (wr % 5) * WIN + t % WIN;
            if (gy >= 64 || gx >= 64) continue;   // pad rows dropped at unpartition
            size_t orow = ((size_t)((bi * 64 + gy) * 64 + gx)) * DIMC;
            #pragma unroll
            for (int j = 0; j < 4; j++) {
                int col = bn + (tx << 2) + j;
                float v = acc[i][j] + bias[col];
                ((float*)Cout)[orow + col] = resid[orow + col] + v;
            }
        } else {
            #pragma unroll
            for (int j = 0; j < 4; j++) {
                int col = bn + (tx << 2) + j;
                float v = acc[i][j] + bias[col];
                if (EPI == 0) {
                    ((unsigned short*)Cout)[(size_t)row * Nn + col] = f2bf(v);
                } else if (EPI == 1) {
                    v = 0.5f * v * (1.f + erff(v * 0.70710678118654752f));
                    ((unsigned short*)Cout)[(size_t)row * Nn + col] = f2bf(v);
                } else {
                    ((float*)Cout)[(size_t)row * Nn + col] =
                        resid[(size_t)row * Nn + col] + v;
                }
            }
        }
    }
}

// ---------------------------------------------------------------------------
extern "C" void kernel_launch(void* const* d_in, const int* in_sizes, int n_in,
                              void* d_out, int out_size, void* d_ws, size_t ws_size,
                              hipStream_t stream) {
    const float* x      = (const float*)d_in[0];
    const float* ln1_g  = (const float*)d_in[1];
    const float* ln1_b  = (const float*)d_in[2];
    const float* qkv_w  = (const float*)d_in[3];
    const float* qkv_b  = (const float*)d_in[4];
    const float* proj_w = (const float*)d_in[5];
    const float* proj_b = (const float*)d_in[6];
    const float* rel_h  = (const float*)d_in[7];
    const float* rel_w  = (const float*)d_in[8];
    const float* ln2_g  = (const float*)d_in[9];
    const float* ln2_b  = (const float*)d_in[10];
    const float* fc1_w  = (const float*)d_in[11];
    const float* fc1_b  = (const float*)d_in[12];
    const float* fc2_w  = (const float*)d_in[13];
    const float* fc2_b  = (const float*)d_in[14];
    float* out = (float*)d_out;
    char* ws = (char*)d_ws;

    // Workspace regions (no liveness overlap; max usage 95,490,048 B):
    //  A [0,        45158400): qkvb bf16 (9800x2304)      [QKV gemm -> attn]
    //        then   yb f32 (8192x768, 25165824 B) @ 0     [proj -> fc2]
    //        and    h2 bf16 (8192x768) @ 25165824          [ln2 -> fc1]
    //  B [45158400, 60211200): h1 bf16 (9800x768)          [ln1 -> QKV gemm]
    //        then   attn_o bf16 (9800x768)                 [attn -> proj]
    //        then   head of zb
    //  C [60211200, 73382400): relh/relw f32 (600x196x14)  [rel -> attn]
    //  zb bf16 (8192x3072, 50331648 B) @ 45158400, ends 95490048  [fc1 -> fc2]
    unsigned short* qkvb   = (unsigned short*)(ws);
    float*          yb     = (float*)        (ws);
    unsigned short* h2     = (unsigned short*)(ws + 25165824);
    unsigned short* h1     = (unsigned short*)(ws + 45158400);
    unsigned short* attn_o = (unsigned short*)(ws + 45158400);
    unsigned short* zb     = (unsigned short*)(ws + 45158400);
    float*          relh_g = (float*)        (ws + 60211200);
    float*          relw_g = (float*)        (ws + 60211200 + 6585600);

    ln1_win_kernel<<<(MROWS + 3) / 4, 256, 0, stream>>>(x, ln1_g, ln1_b, h1);

    gemm_kernel<0><<<dim3(2304 / 64, (MROWS + 63) / 64), 256, 0, stream>>>(
        h1, qkv_w, qkv_b, qkvb, nullptr, MROWS, 2304, DIMC);

    rel_kernel<<<NWIN * HEADS, 256, 0, stream>>>(qkvb, rel_h, rel_w, relh_g, relw_g);

    attn_kernel<<<NWIN * HEADS, 256, 0, stream>>>(qkvb, relh_g, relw_g, attn_o);

    gemm_kernel<2><<<dim3(DIMC / 64, (MROWS + 63) / 64), 256, 0, stream>>>(
        attn_o, proj_w, proj_b, yb, x, MROWS, DIMC, DIMC);

    ln2_kernel<<<YROWS / 4, 256, 0, stream>>>(yb, ln2_g, ln2_b, h2);

    gemm_kernel<1><<<dim3(MLP_HID / 64, YROWS / 64), 256, 0, stream>>>(
        h2, fc1_w, fc1_b, zb, nullptr, YROWS, MLP_HID, DIMC);

    gemm_kernel<3><<<dim3(DIMC / 64, YROWS / 64), 256, 0, stream>>>(
        zb, fc2_w, fc2_b, out, yb, YROWS, DIMC, MLP_HID);
}

// Round 3
// 583.879 us; speedup vs baseline: 6.8476x; 6.8476x over previous
//
#include <hip/hip_runtime.h>
#include <hip/hip_bf16.h>
#include <math.h>

// ---------------------------------------------------------------------------
// Swin/SAM-style block. R3: MFMA GEMMs (bf16, B^T weights) + fused MFMA
// attention with augmented-K rel-pos trick (K=96: 64 qk + 14 relh + 14 relw).
// ---------------------------------------------------------------------------

#define DIMC 768
#define HEADS 12
#define WIN 14
#define NTOK 196
#define NWIN 50
#define MROWS 9800
#define YROWS 8192
#define MLP_HID 3072

using bf16x8 = __attribute__((ext_vector_type(8))) short;
using f32x4  = __attribute__((ext_vector_type(4))) float;

__device__ __forceinline__ float bf2f(unsigned short u) {
    return __uint_as_float(((unsigned)u) << 16);
}
__device__ __forceinline__ unsigned short f2bf(float f) {
    unsigned u = __float_as_uint(f);
    unsigned r = (u + 0x7fffu + ((u >> 16) & 1u)) >> 16;   // round-nearest-even
    return (unsigned short)r;
}

// ---------------- tiled weight transpose: W (K x N, f32) -> Wt (N x K, bf16)
__global__ __launch_bounds__(256) void transpose_w(
        const float* __restrict__ W, unsigned short* __restrict__ Wt,
        int K, int N) {
    __shared__ float t[64][65];
    int k0 = blockIdx.y << 6, n0 = blockIdx.x << 6;
    int tn = threadIdx.x & 63;
    int tk = threadIdx.x >> 6;
    #pragma unroll
    for (int r = 0; r < 16; r++) {
        int k = tk + r * 4;
        t[k][tn] = W[(size_t)(k0 + k) * N + n0 + tn];
    }
    __syncthreads();
    #pragma unroll
    for (int r = 0; r < 16; r++) {
        int n = tk + r * 4;
        Wt[(size_t)(n0 + n) * K + k0 + tn] = f2bf(t[tn][n]);
    }
}

// ---------------- LN1 + window partition (zeros in padding) ----------------
__global__ __launch_bounds__(256) void ln1_win_kernel(
        const float* __restrict__ x, const float* __restrict__ g,
        const float* __restrict__ b, unsigned short* __restrict__ h1) {
    int tid = threadIdx.x;
    int row = blockIdx.x * 4 + (tid >> 6);
    int lane = tid & 63;
    if (row >= MROWS) return;
    int w = row / NTOK, t = row % NTOK;
    int bi = w / 25, wr = w % 25;
    int gy = (wr / 5) * WIN + t / WIN;
    int gx = (wr % 5) * WIN + t % WIN;
    unsigned short* out = h1 + (size_t)row * DIMC;
    if (gy >= 64 || gx >= 64) {           // reference pads AFTER LN -> zeros
        #pragma unroll
        for (int j = 0; j < 12; j++) out[lane + 64 * j] = 0;
        return;
    }
    const float* xr = x + ((size_t)((bi * 64 + gy) * 64 + gx)) * DIMC;
    float v[12], s = 0.f;
    #pragma unroll
    for (int j = 0; j < 12; j++) { v[j] = xr[lane + 64 * j]; s += v[j]; }
    #pragma unroll
    for (int o = 32; o > 0; o >>= 1) s += __shfl_xor(s, o);
    float mean = s * (1.f / 768.f);
    float q = 0.f;
    #pragma unroll
    for (int j = 0; j < 12; j++) { float d = v[j] - mean; q += d * d; }
    #pragma unroll
    for (int o = 32; o > 0; o >>= 1) q += __shfl_xor(q, o);
    float inv = rsqrtf(q * (1.f / 768.f) + 1e-6f);
    #pragma unroll
    for (int j = 0; j < 12; j++) {
        int c = lane + 64 * j;
        out[c] = f2bf((v[j] - mean) * inv * g[c] + b[c]);
    }
}

// ---------------- LN2 ----------------
__global__ __launch_bounds__(256) void ln2_kernel(
        const float* __restrict__ y, const float* __restrict__ g,
        const float* __restrict__ b, unsigned short* __restrict__ h2) {
    int tid = threadIdx.x;
    int row = blockIdx.x * 4 + (tid >> 6);
    int lane = tid & 63;
    const float* xr = y + (size_t)row * DIMC;
    float v[12], s = 0.f;
    #pragma unroll
    for (int j = 0; j < 12; j++) { v[j] = xr[lane + 64 * j]; s += v[j]; }
    #pragma unroll
    for (int o = 32; o > 0; o >>= 1) s += __shfl_xor(s, o);
    float mean = s * (1.f / 768.f);
    float q = 0.f;
    #pragma unroll
    for (int j = 0; j < 12; j++) { float d = v[j] - mean; q += d * d; }
    #pragma unroll
    for (int o = 32; o > 0; o >>= 1) q += __shfl_xor(q, o);
    float inv = rsqrtf(q * (1.f / 768.f) + 1e-6f);
    unsigned short* out = h2 + (size_t)row * DIMC;
    #pragma unroll
    for (int j = 0; j < 12; j++) {
        int c = lane + 64 * j;
        out[c] = f2bf((v[j] - mean) * inv * g[c] + b[c]);
    }
}

// ---------------- build A_aug (q | relh | relw | 0) and Vt per (win,head) ----
__global__ __launch_bounds__(256) void build_aug(
        const unsigned short* __restrict__ qkvb,
        const float* __restrict__ relph, const float* __restrict__ relpw,
        unsigned short* __restrict__ Aaug, unsigned short* __restrict__ Vt) {
    __shared__ unsigned short qs[196 * 72];
    __shared__ unsigned short vls[196 * 72];
    int tid = threadIdx.x;
    int bh = blockIdx.x, w = bh / HEADS, head = bh % HEADS;
    size_t base = (size_t)w * NTOK * 2304 + head * 64;
    unsigned short* ab = Aaug + (size_t)bh * 256 * 96;
    for (int e = tid; e < 196 * 8; e += 256) {
        int t = e >> 3, s8 = (e & 7) * 8;
        bf16x8 qv = *(const bf16x8*)&qkvb[base + (size_t)t * 2304 + s8];
        bf16x8 vv = *(const bf16x8*)&qkvb[base + 1536 + (size_t)t * 2304 + s8];
        *(bf16x8*)&qs[t * 72 + s8] = qv;
        *(bf16x8*)&vls[t * 72 + s8] = vv;
        *(bf16x8*)&ab[t * 96 + s8] = qv;          // A_aug cols 0..63 = q
    }
    bf16x8 z8 = {};
    for (int e = tid; e < 60 * 12; e += 256)       // zero pad rows 196..255
        *(bf16x8*)&ab[(size_t)(196 + e / 12) * 96 + (e % 12) * 8] = z8;
    for (int e = tid; e < 196; e += 256) {         // zero cols 92..95
        ab[e * 96 + 92] = 0; ab[e * 96 + 93] = 0;
        ab[e * 96 + 94] = 0; ab[e * 96 + 95] = 0;
    }
    __syncthreads();
    // rel dots (unscaled q) -> A_aug cols 64..91
    for (int e = tid; e < 196 * 28; e += 256) {
        int i = e / 28, c = e % 28;
        int which = c >= 14;
        int kh = which ? c - 14 : c;
        int pos = which ? (i % WIN) : (i / WIN);
        const float* tab = (which ? relpw : relph) + (size_t)(pos - kh + WIN - 1) * 64;
        const unsigned short* qr = qs + i * 72;
        float sum = 0.f;
        #pragma unroll
        for (int d = 0; d < 64; d++) sum += bf2f(qr[d]) * tab[d];
        ab[i * 96 + 64 + c] = f2bf(sum);
    }
    // Vt: [64][224], cols 196..223 zero
    unsigned short* vtb = Vt + (size_t)bh * 64 * 224;
    for (int e = tid; e < 64 * 28; e += 256) {
        int d = e / 28, j0 = (e % 28) * 8;
        bf16x8 ov;
        #pragma unroll
        for (int jj = 0; jj < 8; jj++)
            ov[jj] = (short)((j0 + jj < 196) ? vls[(j0 + jj) * 72 + d] : 0);
        *(bf16x8*)&vtb[d * 224 + j0] = ov;
    }
}

// ---------------- fused MFMA attention: one block per (window,head) --------
__global__ __launch_bounds__(256) void attn_mfma(
        const unsigned short* __restrict__ qkvb,
        const unsigned short* __restrict__ Aaug,
        const unsigned short* __restrict__ Vt,
        unsigned short* __restrict__ out) {
    __shared__ unsigned short Kls[208 * 96];   // K_aug: [k*0.125 | oh(j/14) | oh(j%14) | 0]
    __shared__ unsigned short Pls[4][64 * 40]; // per-wave P strip, pitch 40
    int tid = threadIdx.x;
    int bh = blockIdx.x, w = bh / HEADS, head = bh % HEADS;
    int wave = tid >> 6, lane = tid & 63;
    int l15 = lane & 15, q4 = lane >> 4, q8 = q4 * 8;
    size_t kbase = (size_t)w * NTOK * 2304 + head * 64 + 768;
    // stage K*0.125 (exact: pow2) rows 0..195
    for (int e = tid; e < 196 * 8; e += 256) {
        int t = e >> 3, s8 = (e & 7) * 8;
        bf16x8 kv = *(const bf16x8*)&qkvb[kbase + (size_t)t * 2304 + s8];
        bf16x8 ko;
        #pragma unroll
        for (int jj = 0; jj < 8; jj++)
            ko[jj] = (short)f2bf(bf2f((unsigned short)kv[jj]) * 0.125f);
        *(bf16x8*)&Kls[t * 96 + s8] = ko;
    }
    bf16x8 z8 = {};
    for (int e = tid; e < 208 * 4; e += 256)   // zero cols 64..95
        *(bf16x8*)&Kls[(e >> 2) * 96 + 64 + (e & 3) * 8] = z8;
    for (int e = tid; e < 12 * 8; e += 256)    // zero rows 196..207 cols 0..63
        *(bf16x8*)&Kls[(196 + (e >> 3)) * 96 + (e & 7) * 8] = z8;
    __syncthreads();                           // zeros before one-hots (same dwords)
    for (int e = tid; e < 196; e += 256) {
        Kls[e * 96 + 64 + e / WIN] = 0x3F80;   // bf16(1.0)
        Kls[e * 96 + 78 + e % WIN] = 0x3F80;
    }
    // A-frags from global (held in regs across all j-tiles)
    bf16x8 af[4][3];
    const unsigned short* abse = Aaug + (size_t)bh * 256 * 96;
    #pragma unroll
    for (int it = 0; it < 4; it++)
        #pragma unroll
        for (int c = 0; c < 3; c++)
            af[it][c] = *(const bf16x8*)&abse[(size_t)(wave * 64 + it * 16 + l15) * 96 + c * 32 + q8];
    __syncthreads();                           // K_aug complete

    const unsigned short* vtb = Vt + (size_t)bh * 64 * 224;
    f32x4 o[4][4] = {};
    float lacc[4][4] = {{0.f}};
    bf16x8 bv[4];
    #pragma unroll
    for (int dt = 0; dt < 4; dt++)
        bv[dt] = *(const bf16x8*)&vtb[(dt * 16 + l15) * 224 + q8];

    for (int jp = 0; jp < 7; jp++) {
        f32x4 s[4][2] = {};
        #pragma unroll
        for (int half = 0; half < 2; half++) {
            int jt = jp * 2 + half;
            if (jt < 13) {
                #pragma unroll
                for (int c = 0; c < 3; c++) {
                    bf16x8 bk = *(bf16x8*)&Kls[(jt * 16 + l15) * 96 + c * 32 + q8];
                    #pragma unroll
                    for (int it = 0; it < 4; it++)
                        s[it][half] = __builtin_amdgcn_mfma_f32_16x16x32_bf16(
                            af[it][c], bk, s[it][half], 0, 0, 0);
                }
            }
        }
        __syncthreads();   // WAR: previous PV reads of Pls complete
        #pragma unroll
        for (int half = 0; half < 2; half++) {
            int jt = jp * 2 + half;
            bool valid = (jt < 13) && (jt * 16 + l15) < 196;
            #pragma unroll
            for (int it = 0; it < 4; it++)
                #pragma unroll
                for (int r = 0; r < 4; r++) {
                    float p = valid ? __expf(s[it][half][r]) : 0.f;
                    unsigned short pb = f2bf(p);
                    lacc[it][r] += bf2f(pb);
                    Pls[wave][(it * 16 + q4 * 4 + r) * 40 + half * 16 + l15] = pb;
                }
        }
        __syncthreads();   // RAW: P visible
        bf16x8 ap[4];
        #pragma unroll
        for (int it = 0; it < 4; it++)
            ap[it] = *(bf16x8*)&Pls[wave][(it * 16 + l15) * 40 + q8];
        bf16x8 bvn[4];
        if (jp < 6) {
            #pragma unroll
            for (int dt = 0; dt < 4; dt++)
                bvn[dt] = *(const bf16x8*)&vtb[(dt * 16 + l15) * 224 + (jp + 1) * 32 + q8];
        }
        #pragma unroll
        for (int dt = 0; dt < 4; dt++)
            #pragma unroll
            for (int it = 0; it < 4; it++)
                o[it][dt] = __builtin_amdgcn_mfma_f32_16x16x32_bf16(
                    ap[it], bv[dt], o[it][dt], 0, 0, 0);
        if (jp < 6) {
            #pragma unroll
            for (int dt = 0; dt < 4; dt++) bv[dt] = bvn[dt];
        }
    }
    // row sums across the 16 j-lanes of each quad
    #pragma unroll
    for (int it = 0; it < 4; it++)
        #pragma unroll
        for (int r = 0; r < 4; r++) {
            float v = lacc[it][r];
            v += __shfl_xor(v, 1); v += __shfl_xor(v, 2);
            v += __shfl_xor(v, 4); v += __shfl_xor(v, 8);
            lacc[it][r] = 1.f / v;
        }
    // store O (win, token, head, d)
    #pragma unroll
    for (int it = 0; it < 4; it++) {
        int i0 = wave * 64 + it * 16 + q4 * 4;
        #pragma unroll
        for (int r = 0; r < 4; r++) {
            if (i0 + r < 196) {
                size_t rowb = (size_t)(w * NTOK + i0 + r) * DIMC + head * 64;
                #pragma unroll
                for (int dt = 0; dt < 4; dt++)
                    out[rowb + dt * 16 + l15] = f2bf(o[it][dt][r] * lacc[it][r]);
            }
        }
    }
}

// ---------------- MFMA GEMM: C = A(M x K, bf16) @ Bt(N x K, bf16)^T + bias --
// EPI 0: bf16 store   EPI 1: exact gelu -> bf16
// EPI 2: window-unpartition + x residual (f32)   EPI 3: + resid (f32)
template <int EPI>
__global__ __launch_bounds__(256) void mgemm(
        const unsigned short* __restrict__ A, const unsigned short* __restrict__ Bt,
        const float* __restrict__ bias, void* __restrict__ Cout,
        const float* __restrict__ resid, int M, int Nn, int K) {
    __shared__ unsigned short As[128 * 32];
    __shared__ unsigned short Bs[128 * 32];
    int tid = threadIdx.x;
    int lane = tid & 63, wave = tid >> 6;
    int l15 = lane & 15, q8 = (lane >> 4) * 8;
    int m0 = blockIdx.y << 7, n0 = blockIdx.x << 7;
    int wm = (wave >> 1) * 64, wn = (wave & 1) * 64;
    f32x4 acc[4][4] = {};
    for (int k0 = 0; k0 < K; k0 += 32) {
        __syncthreads();
        #pragma unroll
        for (int t = 0; t < 2; t++) {
            int idx = t * 256 + tid;
            int rl = idx >> 2, c8 = (idx & 3) * 8;
            int rm = m0 + rl; if (rm >= M) rm = M - 1;
            *(bf16x8*)&As[rl * 32 + c8] = *(const bf16x8*)&A[(size_t)rm * K + k0 + c8];
            *(bf16x8*)&Bs[rl * 32 + c8] = *(const bf16x8*)&Bt[(size_t)(n0 + rl) * K + k0 + c8];
        }
        __syncthreads();
        bf16x8 bfr[4];
        #pragma unroll
        for (int ni = 0; ni < 4; ni++)
            bfr[ni] = *(bf16x8*)&Bs[(wn + ni * 16 + l15) * 32 + q8];
        #pragma unroll
        for (int mi = 0; mi < 4; mi++) {
            bf16x8 afr = *(bf16x8*)&As[(wm + mi * 16 + l15) * 32 + q8];
            #pragma unroll
            for (int ni = 0; ni < 4; ni++)
                acc[mi][ni] = __builtin_amdgcn_mfma_f32_16x16x32_bf16(
                    afr, bfr[ni], acc[mi][ni], 0, 0, 0);
        }
    }
    int q4r = (lane >> 4) * 4;
    #pragma unroll
    for (int mi = 0; mi < 4; mi++) {
        #pragma unroll
        for (int r = 0; r < 4; r++) {
            int row = m0 + wm + mi * 16 + q4r + r;
            if (row >= M) continue;
            if (EPI == 2) {
                int w = row / NTOK, t = row % NTOK;
                int bi = w / 25, wr = w % 25;
                int gy = (wr / 5) * WIN + t / WIN;
                int gx = (wr % 5) * WIN + t % WIN;
                if (gy >= 64 || gx >= 64) continue;
                size_t orow = ((size_t)((bi * 64 + gy) * 64 + gx)) * DIMC;
                #pragma unroll
                for (int ni = 0; ni < 4; ni++) {
                    int col = n0 + wn + ni * 16 + l15;
                    float v = acc[mi][ni][r] + bias[col];
                    ((float*)Cout)[orow + col] = resid[orow + col] + v;
                }
            } else {
                #pragma unroll
                for (int ni = 0; ni < 4; ni++) {
                    int col = n0 + wn + ni * 16 + l15;
                    float v = acc[mi][ni][r] + bias[col];
                    if (EPI == 0) {
                        ((unsigned short*)Cout)[(size_t)row * Nn + col] = f2bf(v);
                    } else if (EPI == 1) {
                        v = 0.5f * v * (1.f + erff(v * 0.70710678118654752f));
                        ((unsigned short*)Cout)[(size_t)row * Nn + col] = f2bf(v);
                    } else {
                        ((float*)Cout)[(size_t)row * Nn + col] =
                            resid[(size_t)row * Nn + col] + v;
                    }
                }
            }
        }
    }
}

// ---------------------------------------------------------------------------
extern "C" void kernel_launch(void* const* d_in, const int* in_sizes, int n_in,
                              void* d_out, int out_size, void* d_ws, size_t ws_size,
                              hipStream_t stream) {
    const float* x      = (const float*)d_in[0];
    const float* ln1_g  = (const float*)d_in[1];
    const float* ln1_b  = (const float*)d_in[2];
    const float* qkv_w  = (const float*)d_in[3];
    const float* qkv_b  = (const float*)d_in[4];
    const float* proj_w = (const float*)d_in[5];
    const float* proj_b = (const float*)d_in[6];
    const float* rel_h  = (const float*)d_in[7];
    const float* rel_w  = (const float*)d_in[8];
    const float* ln2_g  = (const float*)d_in[9];
    const float* ln2_b  = (const float*)d_in[10];
    const float* fc1_w  = (const float*)d_in[11];
    const float* fc1_b  = (const float*)d_in[12];
    const float* fc2_w  = (const float*)d_in[13];
    const float* fc2_b  = (const float*)d_in[14];
    float* out = (float*)d_out;
    char* ws = (char*)d_ws;

    // Workspace (max 121,061,376 B), liveness-checked:
    //  [0,14155776)            wt_* bf16 transposed weights      (whole call)
    //  [14155776,59314176)     qkvb bf16 9800x2304   (T2-T4)
    //     reused: yb f32 8192x768 @14155776 (T5-T8); h2 bf16 @39321600 (T6-T7)
    //  [59314176,74366976)     h1 (T1-T2) -> attn_o (T4-T5) -> zb head (T7-T8)
    //  [74366976,103858176)    Aaug 600x256x96 bf16 (T3-T4); zb tail overlaps after T4
    //  [103858176,121061376)   Vt 600x64x224 bf16 (T3-T4); zb tail overlaps after T4
    unsigned short* wt_qkv  = (unsigned short*)(ws);
    unsigned short* wt_proj = (unsigned short*)(ws + 3538944);
    unsigned short* wt_fc1  = (unsigned short*)(ws + 4718592);
    unsigned short* wt_fc2  = (unsigned short*)(ws + 9437184);
    unsigned short* qkvb    = (unsigned short*)(ws + 14155776);
    float*          yb      = (float*)        (ws + 14155776);
    unsigned short* h2      = (unsigned short*)(ws + 39321600);
    unsigned short* h1      = (unsigned short*)(ws + 59314176);
    unsigned short* attn_o  = h1;
    unsigned short* zb      = h1;
    unsigned short* Aaug    = (unsigned short*)(ws + 74366976);
    unsigned short* Vt      = (unsigned short*)(ws + 103858176);

    transpose_w<<<dim3(36, 12), 256, 0, stream>>>(qkv_w,  wt_qkv,  768, 2304);
    transpose_w<<<dim3(12, 12), 256, 0, stream>>>(proj_w, wt_proj, 768, 768);
    transpose_w<<<dim3(48, 12), 256, 0, stream>>>(fc1_w,  wt_fc1,  768, 3072);
    transpose_w<<<dim3(12, 48), 256, 0, stream>>>(fc2_w,  wt_fc2,  3072, 768);

    ln1_win_kernel<<<(MROWS + 3) / 4, 256, 0, stream>>>(x, ln1_g, ln1_b, h1);

    mgemm<0><<<dim3(18, 77), 256, 0, stream>>>(
        h1, wt_qkv, qkv_b, qkvb, nullptr, MROWS, 2304, DIMC);

    build_aug<<<NWIN * HEADS, 256, 0, stream>>>(qkvb, rel_h, rel_w, Aaug, Vt);

    attn_mfma<<<NWIN * HEADS, 256, 0, stream>>>(qkvb, Aaug, Vt, attn_o);

    mgemm<2><<<dim3(6, 77), 256, 0, stream>>>(
        attn_o, wt_proj, proj_b, yb, x, MROWS, DIMC, DIMC);

    ln2_kernel<<<YROWS / 4, 256, 0, stream>>>(yb, ln2_g, ln2_b, h2);

    mgemm<1><<<dim3(24, 64), 256, 0, stream>>>(
        h2, wt_fc1, fc1_b, zb, nullptr, YROWS, MLP_HID, DIMC);

    mgemm<3><<<dim3(6, 64), 256, 0, stream>>>(
        zb, wt_fc2, fc2_b, out, yb, YROWS, DIMC, MLP_HID);
}

// Round 4
// 488.098 us; speedup vs baseline: 8.1913x; 1.1962x over previous
//
#include <hip/hip_runtime.h>
#include <hip/hip_bf16.h>
#include <math.h>

// ---------------------------------------------------------------------------
// Swin/SAM-style block. R4: build_aug via MFMA rel-dots + scatter (kills 5.8M
// bank conflicts); mgemm pitch-40 LDS (conflict-free frags) + reg prefetch.
// ---------------------------------------------------------------------------

#define DIMC 768
#define HEADS 12
#define WIN 14
#define NTOK 196
#define NWIN 50
#define MROWS 9800
#define YROWS 8192
#define MLP_HID 3072

using bf16x8 = __attribute__((ext_vector_type(8))) short;
using f32x4  = __attribute__((ext_vector_type(4))) float;

__device__ __forceinline__ float bf2f(unsigned short u) {
    return __uint_as_float(((unsigned)u) << 16);
}
__device__ __forceinline__ unsigned short f2bf(float f) {
    unsigned u = __float_as_uint(f);
    unsigned r = (u + 0x7fffu + ((u >> 16) & 1u)) >> 16;   // round-nearest-even
    return (unsigned short)r;
}

// ---------------- tiled weight transpose: W (K x N, f32) -> Wt (N x K, bf16)
__global__ __launch_bounds__(256) void transpose_w(
        const float* __restrict__ W, unsigned short* __restrict__ Wt,
        int K, int N) {
    __shared__ float t[64][65];
    int k0 = blockIdx.y << 6, n0 = blockIdx.x << 6;
    int tn = threadIdx.x & 63;
    int tk = threadIdx.x >> 6;
    #pragma unroll
    for (int r = 0; r < 16; r++) {
        int k = tk + r * 4;
        t[k][tn] = W[(size_t)(k0 + k) * N + n0 + tn];
    }
    __syncthreads();
    #pragma unroll
    for (int r = 0; r < 16; r++) {
        int n = tk + r * 4;
        Wt[(size_t)(n0 + n) * K + k0 + tn] = f2bf(t[tn][n]);
    }
}

// ---------------- LN1 + window partition (zeros in padding) ----------------
__global__ __launch_bounds__(256) void ln1_win_kernel(
        const float* __restrict__ x, const float* __restrict__ g,
        const float* __restrict__ b, unsigned short* __restrict__ h1) {
    int tid = threadIdx.x;
    int row = blockIdx.x * 4 + (tid >> 6);
    int lane = tid & 63;
    if (row >= MROWS) return;
    int w = row / NTOK, t = row % NTOK;
    int bi = w / 25, wr = w % 25;
    int gy = (wr / 5) * WIN + t / WIN;
    int gx = (wr % 5) * WIN + t % WIN;
    unsigned short* out = h1 + (size_t)row * DIMC;
    if (gy >= 64 || gx >= 64) {           // reference pads AFTER LN -> zeros
        #pragma unroll
        for (int j = 0; j < 12; j++) out[lane + 64 * j] = 0;
        return;
    }
    const float* xr = x + ((size_t)((bi * 64 + gy) * 64 + gx)) * DIMC;
    float v[12], s = 0.f;
    #pragma unroll
    for (int j = 0; j < 12; j++) { v[j] = xr[lane + 64 * j]; s += v[j]; }
    #pragma unroll
    for (int o = 32; o > 0; o >>= 1) s += __shfl_xor(s, o);
    float mean = s * (1.f / 768.f);
    float q = 0.f;
    #pragma unroll
    for (int j = 0; j < 12; j++) { float d = v[j] - mean; q += d * d; }
    #pragma unroll
    for (int o = 32; o > 0; o >>= 1) q += __shfl_xor(q, o);
    float inv = rsqrtf(q * (1.f / 768.f) + 1e-6f);
    #pragma unroll
    for (int j = 0; j < 12; j++) {
        int c = lane + 64 * j;
        out[c] = f2bf((v[j] - mean) * inv * g[c] + b[c]);
    }
}

// ---------------- LN2 ----------------
__global__ __launch_bounds__(256) void ln2_kernel(
        const float* __restrict__ y, const float* __restrict__ g,
        const float* __restrict__ b, unsigned short* __restrict__ h2) {
    int tid = threadIdx.x;
    int row = blockIdx.x * 4 + (tid >> 6);
    int lane = tid & 63;
    const float* xr = y + (size_t)row * DIMC;
    float v[12], s = 0.f;
    #pragma unroll
    for (int j = 0; j < 12; j++) { v[j] = xr[lane + 64 * j]; s += v[j]; }
    #pragma unroll
    for (int o = 32; o > 0; o >>= 1) s += __shfl_xor(s, o);
    float mean = s * (1.f / 768.f);
    float q = 0.f;
    #pragma unroll
    for (int j = 0; j < 12; j++) { float d = v[j] - mean; q += d * d; }
    #pragma unroll
    for (int o = 32; o > 0; o >>= 1) q += __shfl_xor(q, o);
    float inv = rsqrtf(q * (1.f / 768.f) + 1e-6f);
    unsigned short* out = h2 + (size_t)row * DIMC;
    #pragma unroll
    for (int j = 0; j < 12; j++) {
        int c = lane + 64 * j;
        out[c] = f2bf((v[j] - mean) * inv * g[c] + b[c]);
    }
}

// ---------------- build A_aug (q | relh | relw | 0) and Vt per (win,head) ----
// rel dots via MFMA: dots[i][r] = q[i] . RT[r], RT = [relph(27) | relpw(27)].
// relh[i][c] = dots[i][13 + i/14 - c]; relw[i][c] = dots[i][27 + 13 + i%14 - c].
__global__ __launch_bounds__(256) void build_aug(
        const unsigned short* __restrict__ qkvb,
        const float* __restrict__ relph, const float* __restrict__ relpw,
        unsigned short* __restrict__ Aaug, unsigned short* __restrict__ Vt) {
    __shared__ unsigned short qs[208 * 72];   // pitch 72: b128-aligned, 2-way banks
    __shared__ unsigned short rt[64 * 72];
    int tid = threadIdx.x;
    int bh = blockIdx.x, w = bh / HEADS, head = bh % HEADS;
    int lane = tid & 63, wave = tid >> 6;
    int l15 = lane & 15, q4 = lane >> 4, q8 = q4 * 8;
    size_t base = (size_t)w * NTOK * 2304 + head * 64;
    unsigned short* ab = Aaug + (size_t)bh * 256 * 96;

    // stage q -> qs, copy to ab cols 0..63
    for (int e = tid; e < 196 * 8; e += 256) {
        int t = e >> 3, s8 = (e & 7) * 8;
        bf16x8 qv = *(const bf16x8*)&qkvb[base + (size_t)t * 2304 + s8];
        *(bf16x8*)&qs[t * 72 + s8] = qv;
        *(bf16x8*)&ab[t * 96 + s8] = qv;
    }
    for (int e = tid; e < 12 * 8; e += 256) {  // zero qs rows 196..207
        bf16x8 z = {};
        *(bf16x8*)&qs[(196 + (e >> 3)) * 72 + (e & 7) * 8] = z;
    }
    // stage RT tables (f32 -> bf16), rows 54..63 zero
    for (int e = tid; e < 64 * 8; e += 256) {
        int r = e >> 3, s8 = (e & 7) * 8;
        bf16x8 ov = {};
        if (r < 54) {
            const float* src = (r < 27 ? relph + (size_t)r * 64
                                       : relpw + (size_t)(r - 27) * 64) + s8;
            #pragma unroll
            for (int jj = 0; jj < 8; jj++) ov[jj] = (short)f2bf(src[jj]);
        }
        *(bf16x8*)&rt[r * 72 + s8] = ov;
    }
    // zero ab rows 196..255 (all 96 cols) and cols 92..95
    for (int e = tid; e < 60 * 12; e += 256) {
        bf16x8 z = {};
        *(bf16x8*)&ab[(size_t)(196 + e / 12) * 96 + (e % 12) * 8] = z;
    }
    for (int e = tid; e < 196; e += 256) {
        ab[e * 96 + 92] = 0; ab[e * 96 + 93] = 0;
        ab[e * 96 + 94] = 0; ab[e * 96 + 95] = 0;
    }
    __syncthreads();

    // rel MFMA + scatter into ab cols 64..91
    #pragma unroll
    for (int t = 0; t < 4; t++) {
        int it = wave * 4 + t;
        if (it >= 13) break;                      // wave-uniform
        bf16x8 a0 = *(bf16x8*)&qs[(it * 16 + l15) * 72 + q8];
        bf16x8 a1 = *(bf16x8*)&qs[(it * 16 + l15) * 72 + 32 + q8];
        #pragma unroll
        for (int rt4 = 0; rt4 < 4; rt4++) {
            bf16x8 b0 = *(bf16x8*)&rt[(rt4 * 16 + l15) * 72 + q8];
            bf16x8 b1 = *(bf16x8*)&rt[(rt4 * 16 + l15) * 72 + 32 + q8];
            f32x4 d4 = {};
            d4 = __builtin_amdgcn_mfma_f32_16x16x32_bf16(a0, b0, d4, 0, 0, 0);
            d4 = __builtin_amdgcn_mfma_f32_16x16x32_bf16(a1, b1, d4, 0, 0, 0);
            int rcol = rt4 * 16 + l15;
            #pragma unroll
            for (int r = 0; r < 4; r++) {
                int i = it * 16 + q4 * 4 + r;
                if (i < 196 && rcol < 54) {
                    if (rcol < 27) {
                        int c = 13 + i / 14 - rcol;
                        if (c >= 0 && c < 14) ab[i * 96 + 64 + c] = f2bf(d4[r]);
                    } else {
                        int c = 13 + i % 14 - (rcol - 27);
                        if (c >= 0 && c < 14) ab[i * 96 + 78 + c] = f2bf(d4[r]);
                    }
                }
            }
        }
    }

    // Vt[d][224]: vector read V, scalar global scatter (L2 write-combines)
    unsigned short* vtb = Vt + (size_t)bh * 64 * 224;
    for (int e = tid; e < 196 * 8; e += 256) {
        int j = e >> 3, dg = (e & 7) * 8;
        bf16x8 vv = *(const bf16x8*)&qkvb[base + 1536 + (size_t)j * 2304 + dg];
        #pragma unroll
        for (int k = 0; k < 8; k++)
            vtb[(size_t)(dg + k) * 224 + j] = (unsigned short)vv[k];
    }
    for (int e = tid; e < 64 * 28; e += 256)     // zero cols 196..223
        vtb[(size_t)(e / 28) * 224 + 196 + (e % 28)] = 0;
}

// ---------------- fused MFMA attention: one block per (window,head) --------
__global__ __launch_bounds__(256) void attn_mfma(
        const unsigned short* __restrict__ qkvb,
        const unsigned short* __restrict__ Aaug,
        const unsigned short* __restrict__ Vt,
        unsigned short* __restrict__ out) {
    __shared__ unsigned short Kls[208 * 96];   // K_aug: [k*0.125 | oh(j/14) | oh(j%14) | 0]
    __shared__ unsigned short Pls[4][64 * 40]; // per-wave P strip, pitch 40
    int tid = threadIdx.x;
    int bh = blockIdx.x, w = bh / HEADS, head = bh % HEADS;
    int wave = tid >> 6, lane = tid & 63;
    int l15 = lane & 15, q4 = lane >> 4, q8 = q4 * 8;
    size_t kbase = (size_t)w * NTOK * 2304 + head * 64 + 768;
    // stage K*0.125 (exact: pow2) rows 0..195
    for (int e = tid; e < 196 * 8; e += 256) {
        int t = e >> 3, s8 = (e & 7) * 8;
        bf16x8 kv = *(const bf16x8*)&qkvb[kbase + (size_t)t * 2304 + s8];
        bf16x8 ko;
        #pragma unroll
        for (int jj = 0; jj < 8; jj++)
            ko[jj] = (short)f2bf(bf2f((unsigned short)kv[jj]) * 0.125f);
        *(bf16x8*)&Kls[t * 96 + s8] = ko;
    }
    bf16x8 z8 = {};
    for (int e = tid; e < 208 * 4; e += 256)   // zero cols 64..95
        *(bf16x8*)&Kls[(e >> 2) * 96 + 64 + (e & 3) * 8] = z8;
    for (int e = tid; e < 12 * 8; e += 256)    // zero rows 196..207 cols 0..63
        *(bf16x8*)&Kls[(196 + (e >> 3)) * 96 + (e & 7) * 8] = z8;
    __syncthreads();                           // zeros before one-hots (same dwords)
    for (int e = tid; e < 196; e += 256) {
        Kls[e * 96 + 64 + e / WIN] = 0x3F80;   // bf16(1.0)
        Kls[e * 96 + 78 + e % WIN] = 0x3F80;
    }
    // A-frags from global (held in regs across all j-tiles)
    bf16x8 af[4][3];
    const unsigned short* abse = Aaug + (size_t)bh * 256 * 96;
    #pragma unroll
    for (int it = 0; it < 4; it++)
        #pragma unroll
        for (int c = 0; c < 3; c++)
            af[it][c] = *(const bf16x8*)&abse[(size_t)(wave * 64 + it * 16 + l15) * 96 + c * 32 + q8];
    __syncthreads();                           // K_aug complete

    const unsigned short* vtb = Vt + (size_t)bh * 64 * 224;
    f32x4 o[4][4] = {};
    float lacc[4][4] = {{0.f}};
    bf16x8 bv[4];
    #pragma unroll
    for (int dt = 0; dt < 4; dt++)
        bv[dt] = *(const bf16x8*)&vtb[(dt * 16 + l15) * 224 + q8];

    for (int jp = 0; jp < 7; jp++) {
        f32x4 s[4][2] = {};
        #pragma unroll
        for (int half = 0; half < 2; half++) {
            int jt = jp * 2 + half;
            if (jt < 13) {
                #pragma unroll
                for (int c = 0; c < 3; c++) {
                    bf16x8 bk = *(bf16x8*)&Kls[(jt * 16 + l15) * 96 + c * 32 + q8];
                    #pragma unroll
                    for (int it = 0; it < 4; it++)
                        s[it][half] = __builtin_amdgcn_mfma_f32_16x16x32_bf16(
                            af[it][c], bk, s[it][half], 0, 0, 0);
                }
            }
        }
        __syncthreads();   // WAR: previous PV reads of Pls complete
        #pragma unroll
        for (int half = 0; half < 2; half++) {
            int jt = jp * 2 + half;
            bool valid = (jt < 13) && (jt * 16 + l15) < 196;
            #pragma unroll
            for (int it = 0; it < 4; it++)
                #pragma unroll
                for (int r = 0; r < 4; r++) {
                    float p = valid ? __expf(s[it][half][r]) : 0.f;
                    unsigned short pb = f2bf(p);
                    lacc[it][r] += bf2f(pb);
                    Pls[wave][(it * 16 + q4 * 4 + r) * 40 + half * 16 + l15] = pb;
                }
        }
        __syncthreads();   // RAW: P visible
        bf16x8 ap[4];
        #pragma unroll
        for (int it = 0; it < 4; it++)
            ap[it] = *(bf16x8*)&Pls[wave][(it * 16 + l15) * 40 + q8];
        bf16x8 bvn[4];
        if (jp < 6) {
            #pragma unroll
            for (int dt = 0; dt < 4; dt++)
                bvn[dt] = *(const bf16x8*)&vtb[(dt * 16 + l15) * 224 + (jp + 1) * 32 + q8];
        }
        #pragma unroll
        for (int dt = 0; dt < 4; dt++)
            #pragma unroll
            for (int it = 0; it < 4; it++)
                o[it][dt] = __builtin_amdgcn_mfma_f32_16x16x32_bf16(
                    ap[it], bv[dt], o[it][dt], 0, 0, 0);
        if (jp < 6) {
            #pragma unroll
            for (int dt = 0; dt < 4; dt++) bv[dt] = bvn[dt];
        }
    }
    // row sums across the 16 j-lanes of each quad
    #pragma unroll
    for (int it = 0; it < 4; it++)
        #pragma unroll
        for (int r = 0; r < 4; r++) {
            float v = lacc[it][r];
            v += __shfl_xor(v, 1); v += __shfl_xor(v, 2);
            v += __shfl_xor(v, 4); v += __shfl_xor(v, 8);
            lacc[it][r] = 1.f / v;
        }
    // store O (win, token, head, d)
    #pragma unroll
    for (int it = 0; it < 4; it++) {
        int i0 = wave * 64 + it * 16 + q4 * 4;
        #pragma unroll
        for (int r = 0; r < 4; r++) {
            if (i0 + r < 196) {
                size_t rowb = (size_t)(w * NTOK + i0 + r) * DIMC + head * 64;
                #pragma unroll
                for (int dt = 0; dt < 4; dt++)
                    out[rowb + dt * 16 + l15] = f2bf(o[it][dt][r] * lacc[it][r]);
            }
        }
    }
}

// ---------------- MFMA GEMM: C = A(M x K, bf16) @ Bt(N x K, bf16)^T + bias --
// pitch-40 LDS (conflict-free frag reads) + register prefetch of next K-tile.
// EPI 0: bf16 store   EPI 1: exact gelu -> bf16
// EPI 2: window-unpartition + x residual (f32)   EPI 3: + resid (f32)
template <int EPI>
__global__ __launch_bounds__(256) void mgemm(
        const unsigned short* __restrict__ A, const unsigned short* __restrict__ Bt,
        const float* __restrict__ bias, void* __restrict__ Cout,
        const float* __restrict__ resid, int M, int Nn, int K) {
    __shared__ unsigned short As[128 * 40];
    __shared__ unsigned short Bs[128 * 40];
    int tid = threadIdx.x;
    int lane = tid & 63, wave = tid >> 6;
    int l15 = lane & 15, q8 = (lane >> 4) * 8;
    int m0 = blockIdx.y << 7, n0 = blockIdx.x << 7;
    int wm = (wave >> 1) * 64, wn = (wave & 1) * 64;
    int rl0 = tid >> 2, c80 = (tid & 3) * 8;
    int rl1 = 64 + rl0;
    int rmA0 = m0 + rl0; if (rmA0 >= M) rmA0 = M - 1;
    int rmA1 = m0 + rl1; if (rmA1 >= M) rmA1 = M - 1;
    const unsigned short* ApA0 = A + (size_t)rmA0 * K + c80;
    const unsigned short* ApA1 = A + (size_t)rmA1 * K + c80;
    const unsigned short* BpB0 = Bt + (size_t)(n0 + rl0) * K + c80;
    const unsigned short* BpB1 = Bt + (size_t)(n0 + rl1) * K + c80;
    bf16x8 pa0 = *(const bf16x8*)ApA0;
    bf16x8 pa1 = *(const bf16x8*)ApA1;
    bf16x8 pb0 = *(const bf16x8*)BpB0;
    bf16x8 pb1 = *(const bf16x8*)BpB1;
    f32x4 acc[4][4] = {};
    for (int k0 = 0;;) {
        *(bf16x8*)&As[rl0 * 40 + c80] = pa0;
        *(bf16x8*)&As[rl1 * 40 + c80] = pa1;
        *(bf16x8*)&Bs[rl0 * 40 + c80] = pb0;
        *(bf16x8*)&Bs[rl1 * 40 + c80] = pb1;
        __syncthreads();
        int kn = k0 + 32;
        if (kn < K) {                       // prefetch next tile into regs
            pa0 = *(const bf16x8*)(ApA0 + kn);
            pa1 = *(const bf16x8*)(ApA1 + kn);
            pb0 = *(const bf16x8*)(BpB0 + kn);
            pb1 = *(const bf16x8*)(BpB1 + kn);
        }
        bf16x8 bfr[4];
        #pragma unroll
        for (int ni = 0; ni < 4; ni++)
            bfr[ni] = *(bf16x8*)&Bs[(wn + ni * 16 + l15) * 40 + q8];
        #pragma unroll
        for (int mi = 0; mi < 4; mi++) {
            bf16x8 afr = *(bf16x8*)&As[(wm + mi * 16 + l15) * 40 + q8];
            #pragma unroll
            for (int ni = 0; ni < 4; ni++)
                acc[mi][ni] = __builtin_amdgcn_mfma_f32_16x16x32_bf16(
                    afr, bfr[ni], acc[mi][ni], 0, 0, 0);
        }
        if (kn >= K) break;
        k0 = kn;
        __syncthreads();
    }
    int q4r = (lane >> 4) * 4;
    #pragma unroll
    for (int mi = 0; mi < 4; mi++) {
        #pragma unroll
        for (int r = 0; r < 4; r++) {
            int row = m0 + wm + mi * 16 + q4r + r;
            if (row >= M) continue;
            if (EPI == 2) {
                int w = row / NTOK, t = row % NTOK;
                int bi = w / 25, wr = w % 25;
                int gy = (wr / 5) * WIN + t / WIN;
                int gx = (wr % 5) * WIN + t % WIN;
                if (gy >= 64 || gx >= 64) continue;
                size_t orow = ((size_t)((bi * 64 + gy) * 64 + gx)) * DIMC;
                #pragma unroll
                for (int ni = 0; ni < 4; ni++) {
                    int col = n0 + wn + ni * 16 + l15;
                    float v = acc[mi][ni][r] + bias[col];
                    ((float*)Cout)[orow + col] = resid[orow + col] + v;
                }
            } else {
                #pragma unroll
                for (int ni = 0; ni < 4; ni++) {
                    int col = n0 + wn + ni * 16 + l15;
                    float v = acc[mi][ni][r] + bias[col];
                    if (EPI == 0) {
                        ((unsigned short*)Cout)[(size_t)row * Nn + col] = f2bf(v);
                    } else if (EPI == 1) {
                        v = 0.5f * v * (1.f + erff(v * 0.70710678118654752f));
                        ((unsigned short*)Cout)[(size_t)row * Nn + col] = f2bf(v);
                    } else {
                        ((float*)Cout)[(size_t)row * Nn + col] =
                            resid[(size_t)row * Nn + col] + v;
                    }
                }
            }
        }
    }
}

// ---------------------------------------------------------------------------
extern "C" void kernel_launch(void* const* d_in, const int* in_sizes, int n_in,
                              void* d_out, int out_size, void* d_ws, size_t ws_size,
                              hipStream_t stream) {
    const float* x      = (const float*)d_in[0];
    const float* ln1_g  = (const float*)d_in[1];
    const float* ln1_b  = (const float*)d_in[2];
    const float* qkv_w  = (const float*)d_in[3];
    const float* qkv_b  = (const float*)d_in[4];
    const float* proj_w = (const float*)d_in[5];
    const float* proj_b = (const float*)d_in[6];
    const float* rel_h  = (const float*)d_in[7];
    const float* rel_w  = (const float*)d_in[8];
    const float* ln2_g  = (const float*)d_in[9];
    const float* ln2_b  = (const float*)d_in[10];
    const float* fc1_w  = (const float*)d_in[11];
    const float* fc1_b  = (const float*)d_in[12];
    const float* fc2_w  = (const float*)d_in[13];
    const float* fc2_b  = (const float*)d_in[14];
    float* out = (float*)d_out;
    char* ws = (char*)d_ws;

    // Workspace (max 121,061,376 B), liveness-checked (same as R3):
    unsigned short* wt_qkv  = (unsigned short*)(ws);
    unsigned short* wt_proj = (unsigned short*)(ws + 3538944);
    unsigned short* wt_fc1  = (unsigned short*)(ws + 4718592);
    unsigned short* wt_fc2  = (unsigned short*)(ws + 9437184);
    unsigned short* qkvb    = (unsigned short*)(ws + 14155776);
    float*          yb      = (float*)        (ws + 14155776);
    unsigned short* h2      = (unsigned short*)(ws + 39321600);
    unsigned short* h1      = (unsigned short*)(ws + 59314176);
    unsigned short* attn_o  = h1;
    unsigned short* zb      = h1;
    unsigned short* Aaug    = (unsigned short*)(ws + 74366976);
    unsigned short* Vt      = (unsigned short*)(ws + 103858176);

    transpose_w<<<dim3(36, 12), 256, 0, stream>>>(qkv_w,  wt_qkv,  768, 2304);
    transpose_w<<<dim3(12, 12), 256, 0, stream>>>(proj_w, wt_proj, 768, 768);
    transpose_w<<<dim3(48, 12), 256, 0, stream>>>(fc1_w,  wt_fc1,  768, 3072);
    transpose_w<<<dim3(12, 48), 256, 0, stream>>>(fc2_w,  wt_fc2,  3072, 768);

    ln1_win_kernel<<<(MROWS + 3) / 4, 256, 0, stream>>>(x, ln1_g, ln1_b, h1);

    mgemm<0><<<dim3(18, 77), 256, 0, stream>>>(
        h1, wt_qkv, qkv_b, qkvb, nullptr, MROWS, 2304, DIMC);

    build_aug<<<NWIN * HEADS, 256, 0, stream>>>(qkvb, rel_h, rel_w, Aaug, Vt);

    attn_mfma<<<NWIN * HEADS, 256, 0, stream>>>(qkvb, Aaug, Vt, attn_o);

    mgemm<2><<<dim3(6, 77), 256, 0, stream>>>(
        attn_o, wt_proj, proj_b, yb, x, MROWS, DIMC, DIMC);

    ln2_kernel<<<YROWS / 4, 256, 0, stream>>>(yb, ln2_g, ln2_b, h2);

    mgemm<1><<<dim3(24, 64), 256, 0, stream>>>(
        h2, wt_fc1, fc1_b, zb, nullptr, YROWS, MLP_HID, DIMC);

    mgemm<3><<<dim3(6, 64), 256, 0, stream>>>(
        zb, wt_fc2, fc2_b, out, yb, YROWS, DIMC, MLP_HID);
}

// Round 5
// 474.365 us; speedup vs baseline: 8.4284x; 1.0290x over previous
//
#include <hip/hip_runtime.h>
#include <hip/hip_bf16.h>
#include <math.h>

// ---------------------------------------------------------------------------
// Swin/SAM-style block. R5: mgemm K-loop -> m97 structure (global_load_lds
// width-16 async staging, contiguous pitch-32 LDS, 2-barrier loop).
// ---------------------------------------------------------------------------

#define DIMC 768
#define HEADS 12
#define WIN 14
#define NTOK 196
#define NWIN 50
#define MROWS 9800
#define YROWS 8192
#define MLP_HID 3072

using bf16x8 = __attribute__((ext_vector_type(8))) short;
using f32x4  = __attribute__((ext_vector_type(4))) float;

__device__ __forceinline__ float bf2f(unsigned short u) {
    return __uint_as_float(((unsigned)u) << 16);
}
__device__ __forceinline__ unsigned short f2bf(float f) {
    unsigned u = __float_as_uint(f);
    unsigned r = (u + 0x7fffu + ((u >> 16) & 1u)) >> 16;   // round-nearest-even
    return (unsigned short)r;
}
__device__ __forceinline__ void gl2lds16(const unsigned short* g, unsigned short* l) {
    __builtin_amdgcn_global_load_lds(
        (const __attribute__((address_space(1))) void*)g,
        (__attribute__((address_space(3))) void*)l, 16, 0, 0);
}

// ---------------- tiled weight transpose: W (K x N, f32) -> Wt (N x K, bf16)
__global__ __launch_bounds__(256) void transpose_w(
        const float* __restrict__ W, unsigned short* __restrict__ Wt,
        int K, int N) {
    __shared__ float t[64][65];
    int k0 = blockIdx.y << 6, n0 = blockIdx.x << 6;
    int tn = threadIdx.x & 63;
    int tk = threadIdx.x >> 6;
    #pragma unroll
    for (int r = 0; r < 16; r++) {
        int k = tk + r * 4;
        t[k][tn] = W[(size_t)(k0 + k) * N + n0 + tn];
    }
    __syncthreads();
    #pragma unroll
    for (int r = 0; r < 16; r++) {
        int n = tk + r * 4;
        Wt[(size_t)(n0 + n) * K + k0 + tn] = f2bf(t[tn][n]);
    }
}

// ---------------- LN1 + window partition (zeros in padding) ----------------
__global__ __launch_bounds__(256) void ln1_win_kernel(
        const float* __restrict__ x, const float* __restrict__ g,
        const float* __restrict__ b, unsigned short* __restrict__ h1) {
    int tid = threadIdx.x;
    int row = blockIdx.x * 4 + (tid >> 6);
    int lane = tid & 63;
    if (row >= MROWS) return;
    int w = row / NTOK, t = row % NTOK;
    int bi = w / 25, wr = w % 25;
    int gy = (wr / 5) * WIN + t / WIN;
    int gx = (wr % 5) * WIN + t % WIN;
    unsigned short* out = h1 + (size_t)row * DIMC;
    if (gy >= 64 || gx >= 64) {           // reference pads AFTER LN -> zeros
        #pragma unroll
        for (int j = 0; j < 12; j++) out[lane + 64 * j] = 0;
        return;
    }
    const float* xr = x + ((size_t)((bi * 64 + gy) * 64 + gx)) * DIMC;
    float v[12], s = 0.f;
    #pragma unroll
    for (int j = 0; j < 12; j++) { v[j] = xr[lane + 64 * j]; s += v[j]; }
    #pragma unroll
    for (int o = 32; o > 0; o >>= 1) s += __shfl_xor(s, o);
    float mean = s * (1.f / 768.f);
    float q = 0.f;
    #pragma unroll
    for (int j = 0; j < 12; j++) { float d = v[j] - mean; q += d * d; }
    #pragma unroll
    for (int o = 32; o > 0; o >>= 1) q += __shfl_xor(q, o);
    float inv = rsqrtf(q * (1.f / 768.f) + 1e-6f);
    #pragma unroll
    for (int j = 0; j < 12; j++) {
        int c = lane + 64 * j;
        out[c] = f2bf((v[j] - mean) * inv * g[c] + b[c]);
    }
}

// ---------------- LN2 ----------------
__global__ __launch_bounds__(256) void ln2_kernel(
        const float* __restrict__ y, const float* __restrict__ g,
        const float* __restrict__ b, unsigned short* __restrict__ h2) {
    int tid = threadIdx.x;
    int row = blockIdx.x * 4 + (tid >> 6);
    int lane = tid & 63;
    const float* xr = y + (size_t)row * DIMC;
    float v[12], s = 0.f;
    #pragma unroll
    for (int j = 0; j < 12; j++) { v[j] = xr[lane + 64 * j]; s += v[j]; }
    #pragma unroll
    for (int o = 32; o > 0; o >>= 1) s += __shfl_xor(s, o);
    float mean = s * (1.f / 768.f);
    float q = 0.f;
    #pragma unroll
    for (int j = 0; j < 12; j++) { float d = v[j] - mean; q += d * d; }
    #pragma unroll
    for (int o = 32; o > 0; o >>= 1) q += __shfl_xor(q, o);
    float inv = rsqrtf(q * (1.f / 768.f) + 1e-6f);
    unsigned short* out = h2 + (size_t)row * DIMC;
    #pragma unroll
    for (int j = 0; j < 12; j++) {
        int c = lane + 64 * j;
        out[c] = f2bf((v[j] - mean) * inv * g[c] + b[c]);
    }
}

// ---------------- build A_aug (q | relh | relw | 0) and Vt per (win,head) ----
// rel dots via MFMA: dots[i][r] = q[i] . RT[r], RT = [relph(27) | relpw(27)].
// relh[i][c] = dots[i][13 + i/14 - c]; relw[i][c] = dots[i][27 + 13 + i%14 - c].
__global__ __launch_bounds__(256) void build_aug(
        const unsigned short* __restrict__ qkvb,
        const float* __restrict__ relph, const float* __restrict__ relpw,
        unsigned short* __restrict__ Aaug, unsigned short* __restrict__ Vt) {
    __shared__ unsigned short qs[208 * 72];   // pitch 72: b128-aligned, 2-way banks
    __shared__ unsigned short rt[64 * 72];
    int tid = threadIdx.x;
    int bh = blockIdx.x, w = bh / HEADS, head = bh % HEADS;
    int lane = tid & 63, wave = tid >> 6;
    int l15 = lane & 15, q4 = lane >> 4, q8 = q4 * 8;
    size_t base = (size_t)w * NTOK * 2304 + head * 64;
    unsigned short* ab = Aaug + (size_t)bh * 256 * 96;

    // stage q -> qs, copy to ab cols 0..63
    for (int e = tid; e < 196 * 8; e += 256) {
        int t = e >> 3, s8 = (e & 7) * 8;
        bf16x8 qv = *(const bf16x8*)&qkvb[base + (size_t)t * 2304 + s8];
        *(bf16x8*)&qs[t * 72 + s8] = qv;
        *(bf16x8*)&ab[t * 96 + s8] = qv;
    }
    for (int e = tid; e < 12 * 8; e += 256) {  // zero qs rows 196..207
        bf16x8 z = {};
        *(bf16x8*)&qs[(196 + (e >> 3)) * 72 + (e & 7) * 8] = z;
    }
    // stage RT tables (f32 -> bf16), rows 54..63 zero
    for (int e = tid; e < 64 * 8; e += 256) {
        int r = e >> 3, s8 = (e & 7) * 8;
        bf16x8 ov = {};
        if (r < 54) {
            const float* src = (r < 27 ? relph + (size_t)r * 64
                                       : relpw + (size_t)(r - 27) * 64) + s8;
            #pragma unroll
            for (int jj = 0; jj < 8; jj++) ov[jj] = (short)f2bf(src[jj]);
        }
        *(bf16x8*)&rt[r * 72 + s8] = ov;
    }
    // zero ab rows 196..255 (all 96 cols) and cols 92..95
    for (int e = tid; e < 60 * 12; e += 256) {
        bf16x8 z = {};
        *(bf16x8*)&ab[(size_t)(196 + e / 12) * 96 + (e % 12) * 8] = z;
    }
    for (int e = tid; e < 196; e += 256) {
        ab[e * 96 + 92] = 0; ab[e * 96 + 93] = 0;
        ab[e * 96 + 94] = 0; ab[e * 96 + 95] = 0;
    }
    __syncthreads();

    // rel MFMA + scatter into ab cols 64..91
    #pragma unroll
    for (int t = 0; t < 4; t++) {
        int it = wave * 4 + t;
        if (it >= 13) break;                      // wave-uniform
        bf16x8 a0 = *(bf16x8*)&qs[(it * 16 + l15) * 72 + q8];
        bf16x8 a1 = *(bf16x8*)&qs[(it * 16 + l15) * 72 + 32 + q8];
        #pragma unroll
        for (int rt4 = 0; rt4 < 4; rt4++) {
            bf16x8 b0 = *(bf16x8*)&rt[(rt4 * 16 + l15) * 72 + q8];
            bf16x8 b1 = *(bf16x8*)&rt[(rt4 * 16 + l15) * 72 + 32 + q8];
            f32x4 d4 = {};
            d4 = __builtin_amdgcn_mfma_f32_16x16x32_bf16(a0, b0, d4, 0, 0, 0);
            d4 = __builtin_amdgcn_mfma_f32_16x16x32_bf16(a1, b1, d4, 0, 0, 0);
            int rcol = rt4 * 16 + l15;
            #pragma unroll
            for (int r = 0; r < 4; r++) {
                int i = it * 16 + q4 * 4 + r;
                if (i < 196 && rcol < 54) {
                    if (rcol < 27) {
                        int c = 13 + i / 14 - rcol;
                        if (c >= 0 && c < 14) ab[i * 96 + 64 + c] = f2bf(d4[r]);
                    } else {
                        int c = 13 + i % 14 - (rcol - 27);
                        if (c >= 0 && c < 14) ab[i * 96 + 78 + c] = f2bf(d4[r]);
                    }
                }
            }
        }
    }

    // Vt[d][224]: vector read V, scalar global scatter (L2 write-combines)
    unsigned short* vtb = Vt + (size_t)bh * 64 * 224;
    for (int e = tid; e < 196 * 8; e += 256) {
        int j = e >> 3, dg = (e & 7) * 8;
        bf16x8 vv = *(const bf16x8*)&qkvb[base + 1536 + (size_t)j * 2304 + dg];
        #pragma unroll
        for (int k = 0; k < 8; k++)
            vtb[(size_t)(dg + k) * 224 + j] = (unsigned short)vv[k];
    }
    for (int e = tid; e < 64 * 28; e += 256)     // zero cols 196..223
        vtb[(size_t)(e / 28) * 224 + 196 + (e % 28)] = 0;
}

// ---------------- fused MFMA attention: one block per (window,head) --------
__global__ __launch_bounds__(256) void attn_mfma(
        const unsigned short* __restrict__ qkvb,
        const unsigned short* __restrict__ Aaug,
        const unsigned short* __restrict__ Vt,
        unsigned short* __restrict__ out) {
    __shared__ unsigned short Kls[208 * 96];   // K_aug: [k*0.125 | oh(j/14) | oh(j%14) | 0]
    __shared__ unsigned short Pls[4][64 * 40]; // per-wave P strip, pitch 40
    int tid = threadIdx.x;
    int bh = blockIdx.x, w = bh / HEADS, head = bh % HEADS;
    int wave = tid >> 6, lane = tid & 63;
    int l15 = lane & 15, q4 = lane >> 4, q8 = q4 * 8;
    size_t kbase = (size_t)w * NTOK * 2304 + head * 64 + 768;
    // stage K*0.125 (exact: pow2) rows 0..195
    for (int e = tid; e < 196 * 8; e += 256) {
        int t = e >> 3, s8 = (e & 7) * 8;
        bf16x8 kv = *(const bf16x8*)&qkvb[kbase + (size_t)t * 2304 + s8];
        bf16x8 ko;
        #pragma unroll
        for (int jj = 0; jj < 8; jj++)
            ko[jj] = (short)f2bf(bf2f((unsigned short)kv[jj]) * 0.125f);
        *(bf16x8*)&Kls[t * 96 + s8] = ko;
    }
    bf16x8 z8 = {};
    for (int e = tid; e < 208 * 4; e += 256)   // zero cols 64..95
        *(bf16x8*)&Kls[(e >> 2) * 96 + 64 + (e & 3) * 8] = z8;
    for (int e = tid; e < 12 * 8; e += 256)    // zero rows 196..207 cols 0..63
        *(bf16x8*)&Kls[(196 + (e >> 3)) * 96 + (e & 7) * 8] = z8;
    __syncthreads();                           // zeros before one-hots (same dwords)
    for (int e = tid; e < 196; e += 256) {
        Kls[e * 96 + 64 + e / WIN] = 0x3F80;   // bf16(1.0)
        Kls[e * 96 + 78 + e % WIN] = 0x3F80;
    }
    // A-frags from global (held in regs across all j-tiles)
    bf16x8 af[4][3];
    const unsigned short* abse = Aaug + (size_t)bh * 256 * 96;
    #pragma unroll
    for (int it = 0; it < 4; it++)
        #pragma unroll
        for (int c = 0; c < 3; c++)
            af[it][c] = *(const bf16x8*)&abse[(size_t)(wave * 64 + it * 16 + l15) * 96 + c * 32 + q8];
    __syncthreads();                           // K_aug complete

    const unsigned short* vtb = Vt + (size_t)bh * 64 * 224;
    f32x4 o[4][4] = {};
    float lacc[4][4] = {{0.f}};
    bf16x8 bv[4];
    #pragma unroll
    for (int dt = 0; dt < 4; dt++)
        bv[dt] = *(const bf16x8*)&vtb[(dt * 16 + l15) * 224 + q8];

    for (int jp = 0; jp < 7; jp++) {
        f32x4 s[4][2] = {};
        #pragma unroll
        for (int half = 0; half < 2; half++) {
            int jt = jp * 2 + half;
            if (jt < 13) {
                #pragma unroll
                for (int c = 0; c < 3; c++) {
                    bf16x8 bk = *(bf16x8*)&Kls[(jt * 16 + l15) * 96 + c * 32 + q8];
                    #pragma unroll
                    for (int it = 0; it < 4; it++)
                        s[it][half] = __builtin_amdgcn_mfma_f32_16x16x32_bf16(
                            af[it][c], bk, s[it][half], 0, 0, 0);
                }
            }
        }
        __syncthreads();   // WAR: previous PV reads of Pls complete
        #pragma unroll
        for (int half = 0; half < 2; half++) {
            int jt = jp * 2 + half;
            bool valid = (jt < 13) && (jt * 16 + l15) < 196;
            #pragma unroll
            for (int it = 0; it < 4; it++)
                #pragma unroll
                for (int r = 0; r < 4; r++) {
                    float p = valid ? __expf(s[it][half][r]) : 0.f;
                    unsigned short pb = f2bf(p);
                    lacc[it][r] += bf2f(pb);
                    Pls[wave][(it * 16 + q4 * 4 + r) * 40 + half * 16 + l15] = pb;
                }
        }
        __syncthreads();   // RAW: P visible
        bf16x8 ap[4];
        #pragma unroll
        for (int it = 0; it < 4; it++)
            ap[it] = *(bf16x8*)&Pls[wave][(it * 16 + l15) * 40 + q8];
        bf16x8 bvn[4];
        if (jp < 6) {
            #pragma unroll
            for (int dt = 0; dt < 4; dt++)
                bvn[dt] = *(const bf16x8*)&vtb[(dt * 16 + l15) * 224 + (jp + 1) * 32 + q8];
        }
        #pragma unroll
        for (int dt = 0; dt < 4; dt++)
            #pragma unroll
            for (int it = 0; it < 4; it++)
                o[it][dt] = __builtin_amdgcn_mfma_f32_16x16x32_bf16(
                    ap[it], bv[dt], o[it][dt], 0, 0, 0);
        if (jp < 6) {
            #pragma unroll
            for (int dt = 0; dt < 4; dt++) bv[dt] = bvn[dt];
        }
    }
    // row sums across the 16 j-lanes of each quad
    #pragma unroll
    for (int it = 0; it < 4; it++)
        #pragma unroll
        for (int r = 0; r < 4; r++) {
            float v = lacc[it][r];
            v += __shfl_xor(v, 1); v += __shfl_xor(v, 2);
            v += __shfl_xor(v, 4); v += __shfl_xor(v, 8);
            lacc[it][r] = 1.f / v;
        }
    // store O (win, token, head, d)
    #pragma unroll
    for (int it = 0; it < 4; it++) {
        int i0 = wave * 64 + it * 16 + q4 * 4;
        #pragma unroll
        for (int r = 0; r < 4; r++) {
            if (i0 + r < 196) {
                size_t rowb = (size_t)(w * NTOK + i0 + r) * DIMC + head * 64;
                #pragma unroll
                for (int dt = 0; dt < 4; dt++)
                    out[rowb + dt * 16 + l15] = f2bf(o[it][dt][r] * lacc[it][r]);
            }
        }
    }
}

// ---------------- MFMA GEMM (m97 structure): C = A @ Bt^T + bias -----------
// global_load_lds width-16 staging into contiguous pitch-32 LDS; 2 barriers.
// EPI 0: bf16 store   EPI 1: exact gelu -> bf16
// EPI 2: window-unpartition + x residual (f32)   EPI 3: + resid (f32)
template <int EPI>
__global__ __launch_bounds__(256) void mgemm(
        const unsigned short* __restrict__ A, const unsigned short* __restrict__ Bt,
        const float* __restrict__ bias, void* __restrict__ Cout,
        const float* __restrict__ resid, int M, int Nn, int K) {
    __shared__ unsigned short As[128 * 32];
    __shared__ unsigned short Bs[128 * 32];
    int tid = threadIdx.x;
    int lane = tid & 63, wave = tid >> 6;
    int l15 = lane & 15, q8 = (lane >> 4) * 8;
    int m0 = blockIdx.y << 7, n0 = blockIdx.x << 7;
    int wm = (wave >> 1) * 64, wn = (wave & 1) * 64;
    // staging: wave wv stages rows 32wv..32wv+31 (2 insts of 16 rows each);
    // lane i -> row i/4, 16B seg i%4  => LDS dst = wavebase + lane*16 (exact order)
    int srow0 = wave * 32 + (lane >> 2);
    int srow1 = srow0 + 16;
    int sseg = (lane & 3) * 8;
    int rmA0 = m0 + srow0; if (rmA0 >= M) rmA0 = M - 1;   // clamp: rows>=M never stored
    int rmA1 = m0 + srow1; if (rmA1 >= M) rmA1 = M - 1;
    const unsigned short* gA0 = A + (size_t)rmA0 * K + sseg;
    const unsigned short* gA1 = A + (size_t)rmA1 * K + sseg;
    const unsigned short* gB0 = Bt + (size_t)(n0 + srow0) * K + sseg;
    const unsigned short* gB1 = Bt + (size_t)(n0 + srow1) * K + sseg;
    unsigned short* lA0 = As + wave * 1024 + lane * 8;
    unsigned short* lA1 = lA0 + 512;
    unsigned short* lB0 = Bs + wave * 1024 + lane * 8;
    unsigned short* lB1 = lB0 + 512;
    f32x4 acc[4][4] = {};
    for (int k0 = 0; k0 < K; k0 += 32) {
        gl2lds16(gA0 + k0, lA0);
        gl2lds16(gA1 + k0, lA1);
        gl2lds16(gB0 + k0, lB0);
        gl2lds16(gB1 + k0, lB1);
        __syncthreads();                     // drains vmcnt + barrier
        bf16x8 bfr[4];
        #pragma unroll
        for (int ni = 0; ni < 4; ni++)
            bfr[ni] = *(bf16x8*)&Bs[(wn + ni * 16 + l15) * 32 + q8];
        #pragma unroll
        for (int mi = 0; mi < 4; mi++) {
            bf16x8 afr = *(bf16x8*)&As[(wm + mi * 16 + l15) * 32 + q8];
            #pragma unroll
            for (int ni = 0; ni < 4; ni++)
                acc[mi][ni] = __builtin_amdgcn_mfma_f32_16x16x32_bf16(
                    afr, bfr[ni], acc[mi][ni], 0, 0, 0);
        }
        __syncthreads();
    }
    int q4r = (lane >> 4) * 4;
    #pragma unroll
    for (int mi = 0; mi < 4; mi++) {
        #pragma unroll
        for (int r = 0; r < 4; r++) {
            int row = m0 + wm + mi * 16 + q4r + r;
            if (row >= M) continue;
            if (EPI == 2) {
                int w = row / NTOK, t = row % NTOK;
                int bi = w / 25, wr = w % 25;
                int gy = (wr / 5) * WIN + t / WIN;
                int gx = (wr % 5) * WIN + t % WIN;
                if (gy >= 64 || gx >= 64) continue;
                size_t orow = ((size_t)((bi * 64 + gy) * 64 + gx)) * DIMC;
                #pragma unroll
                for (int ni = 0; ni < 4; ni++) {
                    int col = n0 + wn + ni * 16 + l15;
                    float v = acc[mi][ni][r] + bias[col];
                    ((float*)Cout)[orow + col] = resid[orow + col] + v;
                }
            } else {
                #pragma unroll
                for (int ni = 0; ni < 4; ni++) {
                    int col = n0 + wn + ni * 16 + l15;
                    float v = acc[mi][ni][r] + bias[col];
                    if (EPI == 0) {
                        ((unsigned short*)Cout)[(size_t)row * Nn + col] = f2bf(v);
                    } else if (EPI == 1) {
                        v = 0.5f * v * (1.f + erff(v * 0.70710678118654752f));
                        ((unsigned short*)Cout)[(size_t)row * Nn + col] = f2bf(v);
                    } else {
                        ((float*)Cout)[(size_t)row * Nn + col] =
                            resid[(size_t)row * Nn + col] + v;
                    }
                }
            }
        }
    }
}

// ---------------------------------------------------------------------------
extern "C" void kernel_launch(void* const* d_in, const int* in_sizes, int n_in,
                              void* d_out, int out_size, void* d_ws, size_t ws_size,
                              hipStream_t stream) {
    const float* x      = (const float*)d_in[0];
    const float* ln1_g  = (const float*)d_in[1];
    const float* ln1_b  = (const float*)d_in[2];
    const float* qkv_w  = (const float*)d_in[3];
    const float* qkv_b  = (const float*)d_in[4];
    const float* proj_w = (const float*)d_in[5];
    const float* proj_b = (const float*)d_in[6];
    const float* rel_h  = (const float*)d_in[7];
    const float* rel_w  = (const float*)d_in[8];
    const float* ln2_g  = (const float*)d_in[9];
    const float* ln2_b  = (const float*)d_in[10];
    const float* fc1_w  = (const float*)d_in[11];
    const float* fc1_b  = (const float*)d_in[12];
    const float* fc2_w  = (const float*)d_in[13];
    const float* fc2_b  = (const float*)d_in[14];
    float* out = (float*)d_out;
    char* ws = (char*)d_ws;

    // Workspace regions (max 121,061,376 B), liveness-checked (same as R3/R4):
    unsigned short* wt_qkv  = (unsigned short*)(ws);
    unsigned short* wt_proj = (unsigned short*)(ws + 3538944);
    unsigned short* wt_fc1  = (unsigned short*)(ws + 4718592);
    unsigned short* wt_fc2  = (unsigned short*)(ws + 9437184);
    unsigned short* qkvb    = (unsigned short*)(ws + 14155776);
    float*          yb      = (float*)        (ws + 14155776);
    unsigned short* h2      = (unsigned short*)(ws + 39321600);
    unsigned short* h1      = (unsigned short*)(ws + 59314176);
    unsigned short* attn_o  = h1;
    unsigned short* zb      = h1;
    unsigned short* Aaug    = (unsigned short*)(ws + 74366976);
    unsigned short* Vt      = (unsigned short*)(ws + 103858176);

    transpose_w<<<dim3(36, 12), 256, 0, stream>>>(qkv_w,  wt_qkv,  768, 2304);
    transpose_w<<<dim3(12, 12), 256, 0, stream>>>(proj_w, wt_proj, 768, 768);
    transpose_w<<<dim3(48, 12), 256, 0, stream>>>(fc1_w,  wt_fc1,  768, 3072);
    transpose_w<<<dim3(12, 48), 256, 0, stream>>>(fc2_w,  wt_fc2,  3072, 768);

    ln1_win_kernel<<<(MROWS + 3) / 4, 256, 0, stream>>>(x, ln1_g, ln1_b, h1);

    mgemm<0><<<dim3(18, 77), 256, 0, stream>>>(
        h1, wt_qkv, qkv_b, qkvb, nullptr, MROWS, 2304, DIMC);

    build_aug<<<NWIN * HEADS, 256, 0, stream>>>(qkvb, rel_h, rel_w, Aaug, Vt);

    attn_mfma<<<NWIN * HEADS, 256, 0, stream>>>(qkvb, Aaug, Vt, attn_o);

    mgemm<2><<<dim3(6, 77), 256, 0, stream>>>(
        attn_o, wt_proj, proj_b, yb, x, MROWS, DIMC, DIMC);

    ln2_kernel<<<YROWS / 4, 256, 0, stream>>>(yb, ln2_g, ln2_b, h2);

    mgemm<1><<<dim3(24, 64), 256, 0, stream>>>(
        h2, wt_fc1, fc1_b, zb, nullptr, YROWS, MLP_HID, DIMC);

    mgemm<3><<<dim3(6, 64), 256, 0, stream>>>(
        zb, wt_fc2, fc2_b, out, yb, YROWS, DIMC, MLP_HID);
}

// Round 6
// 452.027 us; speedup vs baseline: 8.8449x; 1.0494x over previous
//
#include <hip/hip_runtime.h>
#include <hip/hip_bf16.h>
#include <math.h>

// ---------------------------------------------------------------------------
// Swin/SAM-style block. R6: XCD-aware block swizzle for mgemm (A-tile reuse
// within per-XCD L2) + BN=64 tiles for proj/fc2 (2x blocks, latency hiding).
// ---------------------------------------------------------------------------

#define DIMC 768
#define HEADS 12
#define WIN 14
#define NTOK 196
#define NWIN 50
#define MROWS 9800
#define YROWS 8192
#define MLP_HID 3072

using bf16x8 = __attribute__((ext_vector_type(8))) short;
using f32x4  = __attribute__((ext_vector_type(4))) float;

__device__ __forceinline__ float bf2f(unsigned short u) {
    return __uint_as_float(((unsigned)u) << 16);
}
__device__ __forceinline__ unsigned short f2bf(float f) {
    unsigned u = __float_as_uint(f);
    unsigned r = (u + 0x7fffu + ((u >> 16) & 1u)) >> 16;   // round-nearest-even
    return (unsigned short)r;
}
__device__ __forceinline__ void gl2lds16(const unsigned short* g, unsigned short* l) {
    __builtin_amdgcn_global_load_lds(
        (const __attribute__((address_space(1))) void*)g,
        (__attribute__((address_space(3))) void*)l, 16, 0, 0);
}

// ---------------- tiled weight transpose: W (K x N, f32) -> Wt (N x K, bf16)
__global__ __launch_bounds__(256) void transpose_w(
        const float* __restrict__ W, unsigned short* __restrict__ Wt,
        int K, int N) {
    __shared__ float t[64][65];
    int k0 = blockIdx.y << 6, n0 = blockIdx.x << 6;
    int tn = threadIdx.x & 63;
    int tk = threadIdx.x >> 6;
    #pragma unroll
    for (int r = 0; r < 16; r++) {
        int k = tk + r * 4;
        t[k][tn] = W[(size_t)(k0 + k) * N + n0 + tn];
    }
    __syncthreads();
    #pragma unroll
    for (int r = 0; r < 16; r++) {
        int n = tk + r * 4;
        Wt[(size_t)(n0 + n) * K + k0 + tn] = f2bf(t[tn][n]);
    }
}

// ---------------- LN1 + window partition (zeros in padding) ----------------
__global__ __launch_bounds__(256) void ln1_win_kernel(
        const float* __restrict__ x, const float* __restrict__ g,
        const float* __restrict__ b, unsigned short* __restrict__ h1) {
    int tid = threadIdx.x;
    int row = blockIdx.x * 4 + (tid >> 6);
    int lane = tid & 63;
    if (row >= MROWS) return;
    int w = row / NTOK, t = row % NTOK;
    int bi = w / 25, wr = w % 25;
    int gy = (wr / 5) * WIN + t / WIN;
    int gx = (wr % 5) * WIN + t % WIN;
    unsigned short* out = h1 + (size_t)row * DIMC;
    if (gy >= 64 || gx >= 64) {           // reference pads AFTER LN -> zeros
        #pragma unroll
        for (int j = 0; j < 12; j++) out[lane + 64 * j] = 0;
        return;
    }
    const float* xr = x + ((size_t)((bi * 64 + gy) * 64 + gx)) * DIMC;
    float v[12], s = 0.f;
    #pragma unroll
    for (int j = 0; j < 12; j++) { v[j] = xr[lane + 64 * j]; s += v[j]; }
    #pragma unroll
    for (int o = 32; o > 0; o >>= 1) s += __shfl_xor(s, o);
    float mean = s * (1.f / 768.f);
    float q = 0.f;
    #pragma unroll
    for (int j = 0; j < 12; j++) { float d = v[j] - mean; q += d * d; }
    #pragma unroll
    for (int o = 32; o > 0; o >>= 1) q += __shfl_xor(q, o);
    float inv = rsqrtf(q * (1.f / 768.f) + 1e-6f);
    #pragma unroll
    for (int j = 0; j < 12; j++) {
        int c = lane + 64 * j;
        out[c] = f2bf((v[j] - mean) * inv * g[c] + b[c]);
    }
}

// ---------------- LN2 ----------------
__global__ __launch_bounds__(256) void ln2_kernel(
        const float* __restrict__ y, const float* __restrict__ g,
        const float* __restrict__ b, unsigned short* __restrict__ h2) {
    int tid = threadIdx.x;
    int row = blockIdx.x * 4 + (tid >> 6);
    int lane = tid & 63;
    const float* xr = y + (size_t)row * DIMC;
    float v[12], s = 0.f;
    #pragma unroll
    for (int j = 0; j < 12; j++) { v[j] = xr[lane + 64 * j]; s += v[j]; }
    #pragma unroll
    for (int o = 32; o > 0; o >>= 1) s += __shfl_xor(s, o);
    float mean = s * (1.f / 768.f);
    float q = 0.f;
    #pragma unroll
    for (int j = 0; j < 12; j++) { float d = v[j] - mean; q += d * d; }
    #pragma unroll
    for (int o = 32; o > 0; o >>= 1) q += __shfl_xor(q, o);
    float inv = rsqrtf(q * (1.f / 768.f) + 1e-6f);
    unsigned short* out = h2 + (size_t)row * DIMC;
    #pragma unroll
    for (int j = 0; j < 12; j++) {
        int c = lane + 64 * j;
        out[c] = f2bf((v[j] - mean) * inv * g[c] + b[c]);
    }
}

// ---------------- build A_aug (q | relh | relw | 0) and Vt per (win,head) ----
// rel dots via MFMA: dots[i][r] = q[i] . RT[r], RT = [relph(27) | relpw(27)].
// relh[i][c] = dots[i][13 + i/14 - c]; relw[i][c] = dots[i][27 + 13 + i%14 - c].
__global__ __launch_bounds__(256) void build_aug(
        const unsigned short* __restrict__ qkvb,
        const float* __restrict__ relph, const float* __restrict__ relpw,
        unsigned short* __restrict__ Aaug, unsigned short* __restrict__ Vt) {
    __shared__ unsigned short qs[208 * 72];   // pitch 72: b128-aligned, 2-way banks
    __shared__ unsigned short rt[64 * 72];
    int tid = threadIdx.x;
    int bh = blockIdx.x, w = bh / HEADS, head = bh % HEADS;
    int lane = tid & 63, wave = tid >> 6;
    int l15 = lane & 15, q4 = lane >> 4, q8 = q4 * 8;
    size_t base = (size_t)w * NTOK * 2304 + head * 64;
    unsigned short* ab = Aaug + (size_t)bh * 256 * 96;

    // stage q -> qs, copy to ab cols 0..63
    for (int e = tid; e < 196 * 8; e += 256) {
        int t = e >> 3, s8 = (e & 7) * 8;
        bf16x8 qv = *(const bf16x8*)&qkvb[base + (size_t)t * 2304 + s8];
        *(bf16x8*)&qs[t * 72 + s8] = qv;
        *(bf16x8*)&ab[t * 96 + s8] = qv;
    }
    for (int e = tid; e < 12 * 8; e += 256) {  // zero qs rows 196..207
        bf16x8 z = {};
        *(bf16x8*)&qs[(196 + (e >> 3)) * 72 + (e & 7) * 8] = z;
    }
    // stage RT tables (f32 -> bf16), rows 54..63 zero
    for (int e = tid; e < 64 * 8; e += 256) {
        int r = e >> 3, s8 = (e & 7) * 8;
        bf16x8 ov = {};
        if (r < 54) {
            const float* src = (r < 27 ? relph + (size_t)r * 64
                                       : relpw + (size_t)(r - 27) * 64) + s8;
            #pragma unroll
            for (int jj = 0; jj < 8; jj++) ov[jj] = (short)f2bf(src[jj]);
        }
        *(bf16x8*)&rt[r * 72 + s8] = ov;
    }
    // zero ab rows 196..255 (all 96 cols) and cols 92..95
    for (int e = tid; e < 60 * 12; e += 256) {
        bf16x8 z = {};
        *(bf16x8*)&ab[(size_t)(196 + e / 12) * 96 + (e % 12) * 8] = z;
    }
    for (int e = tid; e < 196; e += 256) {
        ab[e * 96 + 92] = 0; ab[e * 96 + 93] = 0;
        ab[e * 96 + 94] = 0; ab[e * 96 + 95] = 0;
    }
    __syncthreads();

    // rel MFMA + scatter into ab cols 64..91
    #pragma unroll
    for (int t = 0; t < 4; t++) {
        int it = wave * 4 + t;
        if (it >= 13) break;                      // wave-uniform
        bf16x8 a0 = *(bf16x8*)&qs[(it * 16 + l15) * 72 + q8];
        bf16x8 a1 = *(bf16x8*)&qs[(it * 16 + l15) * 72 + 32 + q8];
        #pragma unroll
        for (int rt4 = 0; rt4 < 4; rt4++) {
            bf16x8 b0 = *(bf16x8*)&rt[(rt4 * 16 + l15) * 72 + q8];
            bf16x8 b1 = *(bf16x8*)&rt[(rt4 * 16 + l15) * 72 + 32 + q8];
            f32x4 d4 = {};
            d4 = __builtin_amdgcn_mfma_f32_16x16x32_bf16(a0, b0, d4, 0, 0, 0);
            d4 = __builtin_amdgcn_mfma_f32_16x16x32_bf16(a1, b1, d4, 0, 0, 0);
            int rcol = rt4 * 16 + l15;
            #pragma unroll
            for (int r = 0; r < 4; r++) {
                int i = it * 16 + q4 * 4 + r;
                if (i < 196 && rcol < 54) {
                    if (rcol < 27) {
                        int c = 13 + i / 14 - rcol;
                        if (c >= 0 && c < 14) ab[i * 96 + 64 + c] = f2bf(d4[r]);
                    } else {
                        int c = 13 + i % 14 - (rcol - 27);
                        if (c >= 0 && c < 14) ab[i * 96 + 78 + c] = f2bf(d4[r]);
                    }
                }
            }
        }
    }

    // Vt[d][224]: vector read V, scalar global scatter (L2 write-combines)
    unsigned short* vtb = Vt + (size_t)bh * 64 * 224;
    for (int e = tid; e < 196 * 8; e += 256) {
        int j = e >> 3, dg = (e & 7) * 8;
        bf16x8 vv = *(const bf16x8*)&qkvb[base + 1536 + (size_t)j * 2304 + dg];
        #pragma unroll
        for (int k = 0; k < 8; k++)
            vtb[(size_t)(dg + k) * 224 + j] = (unsigned short)vv[k];
    }
    for (int e = tid; e < 64 * 28; e += 256)     // zero cols 196..223
        vtb[(size_t)(e / 28) * 224 + 196 + (e % 28)] = 0;
}

// ---------------- fused MFMA attention: one block per (window,head) --------
__global__ __launch_bounds__(256) void attn_mfma(
        const unsigned short* __restrict__ qkvb,
        const unsigned short* __restrict__ Aaug,
        const unsigned short* __restrict__ Vt,
        unsigned short* __restrict__ out) {
    __shared__ unsigned short Kls[208 * 96];   // K_aug: [k*0.125 | oh(j/14) | oh(j%14) | 0]
    __shared__ unsigned short Pls[4][64 * 40]; // per-wave P strip, pitch 40
    int tid = threadIdx.x;
    int bh = blockIdx.x, w = bh / HEADS, head = bh % HEADS;
    int wave = tid >> 6, lane = tid & 63;
    int l15 = lane & 15, q4 = lane >> 4, q8 = q4 * 8;
    size_t kbase = (size_t)w * NTOK * 2304 + head * 64 + 768;
    // stage K*0.125 (exact: pow2) rows 0..195
    for (int e = tid; e < 196 * 8; e += 256) {
        int t = e >> 3, s8 = (e & 7) * 8;
        bf16x8 kv = *(const bf16x8*)&qkvb[kbase + (size_t)t * 2304 + s8];
        bf16x8 ko;
        #pragma unroll
        for (int jj = 0; jj < 8; jj++)
            ko[jj] = (short)f2bf(bf2f((unsigned short)kv[jj]) * 0.125f);
        *(bf16x8*)&Kls[t * 96 + s8] = ko;
    }
    bf16x8 z8 = {};
    for (int e = tid; e < 208 * 4; e += 256)   // zero cols 64..95
        *(bf16x8*)&Kls[(e >> 2) * 96 + 64 + (e & 3) * 8] = z8;
    for (int e = tid; e < 12 * 8; e += 256)    // zero rows 196..207 cols 0..63
        *(bf16x8*)&Kls[(196 + (e >> 3)) * 96 + (e & 7) * 8] = z8;
    __syncthreads();                           // zeros before one-hots (same dwords)
    for (int e = tid; e < 196; e += 256) {
        Kls[e * 96 + 64 + e / WIN] = 0x3F80;   // bf16(1.0)
        Kls[e * 96 + 78 + e % WIN] = 0x3F80;
    }
    // A-frags from global (held in regs across all j-tiles)
    bf16x8 af[4][3];
    const unsigned short* abse = Aaug + (size_t)bh * 256 * 96;
    #pragma unroll
    for (int it = 0; it < 4; it++)
        #pragma unroll
        for (int c = 0; c < 3; c++)
            af[it][c] = *(const bf16x8*)&abse[(size_t)(wave * 64 + it * 16 + l15) * 96 + c * 32 + q8];
    __syncthreads();                           // K_aug complete

    const unsigned short* vtb = Vt + (size_t)bh * 64 * 224;
    f32x4 o[4][4] = {};
    float lacc[4][4] = {{0.f}};
    bf16x8 bv[4];
    #pragma unroll
    for (int dt = 0; dt < 4; dt++)
        bv[dt] = *(const bf16x8*)&vtb[(dt * 16 + l15) * 224 + q8];

    for (int jp = 0; jp < 7; jp++) {
        f32x4 s[4][2] = {};
        #pragma unroll
        for (int half = 0; half < 2; half++) {
            int jt = jp * 2 + half;
            if (jt < 13) {
                #pragma unroll
                for (int c = 0; c < 3; c++) {
                    bf16x8 bk = *(bf16x8*)&Kls[(jt * 16 + l15) * 96 + c * 32 + q8];
                    #pragma unroll
                    for (int it = 0; it < 4; it++)
                        s[it][half] = __builtin_amdgcn_mfma_f32_16x16x32_bf16(
                            af[it][c], bk, s[it][half], 0, 0, 0);
                }
            }
        }
        __syncthreads();   // WAR: previous PV reads of Pls complete
        #pragma unroll
        for (int half = 0; half < 2; half++) {
            int jt = jp * 2 + half;
            bool valid = (jt < 13) && (jt * 16 + l15) < 196;
            #pragma unroll
            for (int it = 0; it < 4; it++)
                #pragma unroll
                for (int r = 0; r < 4; r++) {
                    float p = valid ? __expf(s[it][half][r]) : 0.f;
                    unsigned short pb = f2bf(p);
                    lacc[it][r] += bf2f(pb);
                    Pls[wave][(it * 16 + q4 * 4 + r) * 40 + half * 16 + l15] = pb;
                }
        }
        __syncthreads();   // RAW: P visible
        bf16x8 ap[4];
        #pragma unroll
        for (int it = 0; it < 4; it++)
            ap[it] = *(bf16x8*)&Pls[wave][(it * 16 + l15) * 40 + q8];
        bf16x8 bvn[4];
        if (jp < 6) {
            #pragma unroll
            for (int dt = 0; dt < 4; dt++)
                bvn[dt] = *(const bf16x8*)&vtb[(dt * 16 + l15) * 224 + (jp + 1) * 32 + q8];
        }
        #pragma unroll
        for (int dt = 0; dt < 4; dt++)
            #pragma unroll
            for (int it = 0; it < 4; it++)
                o[it][dt] = __builtin_amdgcn_mfma_f32_16x16x32_bf16(
                    ap[it], bv[dt], o[it][dt], 0, 0, 0);
        if (jp < 6) {
            #pragma unroll
            for (int dt = 0; dt < 4; dt++) bv[dt] = bvn[dt];
        }
    }
    // row sums across the 16 j-lanes of each quad
    #pragma unroll
    for (int it = 0; it < 4; it++)
        #pragma unroll
        for (int r = 0; r < 4; r++) {
            float v = lacc[it][r];
            v += __shfl_xor(v, 1); v += __shfl_xor(v, 2);
            v += __shfl_xor(v, 4); v += __shfl_xor(v, 8);
            lacc[it][r] = 1.f / v;
        }
    // store O (win, token, head, d)
    #pragma unroll
    for (int it = 0; it < 4; it++) {
        int i0 = wave * 64 + it * 16 + q4 * 4;
        #pragma unroll
        for (int r = 0; r < 4; r++) {
            if (i0 + r < 196) {
                size_t rowb = (size_t)(w * NTOK + i0 + r) * DIMC + head * 64;
                #pragma unroll
                for (int dt = 0; dt < 4; dt++)
                    out[rowb + dt * 16 + l15] = f2bf(o[it][dt][r] * lacc[it][r]);
            }
        }
    }
}

// ---------------- MFMA GEMM (m97 structure + XCD swizzle): ------------------
// C = A(MxK bf16) @ Bt(NxK bf16)^T + bias.  BM=128, BN in {128,64}, BK=32.
// 1-D grid, id = s*(8*nbx) + bx*rmax + r, by = 8s + r: all bx sharing an
// A-row-tile land on one XCD (id mod 8 const) consecutively -> L2 reuse.
// EPI 0: bf16 store   EPI 1: exact gelu -> bf16
// EPI 2: window-unpartition + x residual (f32)   EPI 3: + resid (f32)
template <int EPI, int BN>
__global__ __launch_bounds__(256) void mgemm(
        const unsigned short* __restrict__ A, const unsigned short* __restrict__ Bt,
        const float* __restrict__ bias, void* __restrict__ Cout,
        const float* __restrict__ resid, int M, int Nn, int K,
        int nbx, int nby) {
    const int NI = BN / 32;                 // per-wave n-frags
    __shared__ unsigned short As[128 * 32];
    __shared__ unsigned short Bs[BN * 32];
    int tid = threadIdx.x;
    int lane = tid & 63, wave = tid >> 6;
    int l15 = lane & 15, q8 = (lane >> 4) * 8;
    // ---- XCD swizzle ----
    int id = blockIdx.x;
    int per = nbx * 8;
    int s = id / per;
    int rem = id - s * per;
    int rmax = nby - s * 8; if (rmax > 8) rmax = 8;
    int bx = rem / rmax;
    int r_ = rem - bx * rmax;
    int by = s * 8 + r_;
    int m0 = by << 7, n0 = bx * BN;
    int wm = (wave >> 1) * 64, wn = (wave & 1) * (BN / 2);
    // staging: lane i -> row i/4, 16B seg i%4 => LDS dst = wavebase + lane*16
    int srow0 = wave * 32 + (lane >> 2);
    int srow1 = srow0 + 16;
    int sseg = (lane & 3) * 8;
    int rmA0 = m0 + srow0; if (rmA0 >= M) rmA0 = M - 1;   // clamp: rows>=M never stored
    int rmA1 = m0 + srow1; if (rmA1 >= M) rmA1 = M - 1;
    const unsigned short* gA0 = A + (size_t)rmA0 * K + sseg;
    const unsigned short* gA1 = A + (size_t)rmA1 * K + sseg;
    unsigned short* lA0 = As + wave * 1024 + lane * 8;
    unsigned short* lA1 = lA0 + 512;
    int browB = (BN == 128) ? srow0 : (wave * 16 + (lane >> 2));
    const unsigned short* gB0 = Bt + (size_t)(n0 + browB) * K + sseg;
    const unsigned short* gB1 = Bt + (size_t)(n0 + srow1) * K + sseg;  // BN=128 only
    unsigned short* lB0 = Bs + ((BN == 128) ? wave * 1024 : wave * 512) + lane * 8;
    unsigned short* lB1 = lB0 + 512;
    f32x4 acc[4][NI] = {};
    for (int k0 = 0; k0 < K; k0 += 32) {
        gl2lds16(gA0 + k0, lA0);
        gl2lds16(gA1 + k0, lA1);
        gl2lds16(gB0 + k0, lB0);
        if (BN == 128) gl2lds16(gB1 + k0, lB1);
        __syncthreads();                     // drains vmcnt + barrier
        bf16x8 bfr[NI];
        #pragma unroll
        for (int ni = 0; ni < NI; ni++)
            bfr[ni] = *(bf16x8*)&Bs[(wn + ni * 16 + l15) * 32 + q8];
        #pragma unroll
        for (int mi = 0; mi < 4; mi++) {
            bf16x8 afr = *(bf16x8*)&As[(wm + mi * 16 + l15) * 32 + q8];
            #pragma unroll
            for (int ni = 0; ni < NI; ni++)
                acc[mi][ni] = __builtin_amdgcn_mfma_f32_16x16x32_bf16(
                    afr, bfr[ni], acc[mi][ni], 0, 0, 0);
        }
        __syncthreads();
    }
    int q4r = (lane >> 4) * 4;
    #pragma unroll
    for (int mi = 0; mi < 4; mi++) {
        #pragma unroll
        for (int r = 0; r < 4; r++) {
            int row = m0 + wm + mi * 16 + q4r + r;
            if (row >= M) continue;
            if (EPI == 2) {
                int w = row / NTOK, t = row % NTOK;
                int bi = w / 25, wr = w % 25;
                int gy = (wr / 5) * WIN + t / WIN;
                int gx = (wr % 5) * WIN + t % WIN;
                if (gy >= 64 || gx >= 64) continue;
                size_t orow = ((size_t)((bi * 64 + gy) * 64 + gx)) * DIMC;
                #pragma unroll
                for (int ni = 0; ni < NI; ni++) {
                    int col = n0 + wn + ni * 16 + l15;
                    float v = acc[mi][ni][r] + bias[col];
                    ((float*)Cout)[orow + col] = resid[orow + col] + v;
                }
            } else {
                #pragma unroll
                for (int ni = 0; ni < NI; ni++) {
                    int col = n0 + wn + ni * 16 + l15;
                    float v = acc[mi][ni][r] + bias[col];
                    if (EPI == 0) {
                        ((unsigned short*)Cout)[(size_t)row * Nn + col] = f2bf(v);
                    } else if (EPI == 1) {
                        v = 0.5f * v * (1.f + erff(v * 0.70710678118654752f));
                        ((unsigned short*)Cout)[(size_t)row * Nn + col] = f2bf(v);
                    } else {
                        ((float*)Cout)[(size_t)row * Nn + col] =
                            resid[(size_t)row * Nn + col] + v;
                    }
                }
            }
        }
    }
}

// ---------------------------------------------------------------------------
extern "C" void kernel_launch(void* const* d_in, const int* in_sizes, int n_in,
                              void* d_out, int out_size, void* d_ws, size_t ws_size,
                              hipStream_t stream) {
    const float* x      = (const float*)d_in[0];
    const float* ln1_g  = (const float*)d_in[1];
    const float* ln1_b  = (const float*)d_in[2];
    const float* qkv_w  = (const float*)d_in[3];
    const float* qkv_b  = (const float*)d_in[4];
    const float* proj_w = (const float*)d_in[5];
    const float* proj_b = (const float*)d_in[6];
    const float* rel_h  = (const float*)d_in[7];
    const float* rel_w  = (const float*)d_in[8];
    const float* ln2_g  = (const float*)d_in[9];
    const float* ln2_b  = (const float*)d_in[10];
    const float* fc1_w  = (const float*)d_in[11];
    const float* fc1_b  = (const float*)d_in[12];
    const float* fc2_w  = (const float*)d_in[13];
    const float* fc2_b  = (const float*)d_in[14];
    float* out = (float*)d_out;
    char* ws = (char*)d_ws;

    // Workspace regions (max 121,061,376 B), liveness-checked (same as R3-R5):
    unsigned short* wt_qkv  = (unsigned short*)(ws);
    unsigned short* wt_proj = (unsigned short*)(ws + 3538944);
    unsigned short* wt_fc1  = (unsigned short*)(ws + 4718592);
    unsigned short* wt_fc2  = (unsigned short*)(ws + 9437184);
    unsigned short* qkvb    = (unsigned short*)(ws + 14155776);
    float*          yb      = (float*)        (ws + 14155776);
    unsigned short* h2      = (unsigned short*)(ws + 39321600);
    unsigned short* h1      = (unsigned short*)(ws + 59314176);
    unsigned short* attn_o  = h1;
    unsigned short* zb      = h1;
    unsigned short* Aaug    = (unsigned short*)(ws + 74366976);
    unsigned short* Vt      = (unsigned short*)(ws + 103858176);

    transpose_w<<<dim3(36, 12), 256, 0, stream>>>(qkv_w,  wt_qkv,  768, 2304);
    transpose_w<<<dim3(12, 12), 256, 0, stream>>>(proj_w, wt_proj, 768, 768);
    transpose_w<<<dim3(48, 12), 256, 0, stream>>>(fc1_w,  wt_fc1,  768, 3072);
    transpose_w<<<dim3(12, 48), 256, 0, stream>>>(fc2_w,  wt_fc2,  3072, 768);

    ln1_win_kernel<<<(MROWS + 3) / 4, 256, 0, stream>>>(x, ln1_g, ln1_b, h1);

    mgemm<0, 128><<<18 * 77, 256, 0, stream>>>(
        h1, wt_qkv, qkv_b, qkvb, nullptr, MROWS, 2304, DIMC, 18, 77);

    build_aug<<<NWIN * HEADS, 256, 0, stream>>>(qkvb, rel_h, rel_w, Aaug, Vt);

    attn_mfma<<<NWIN * HEADS, 256, 0, stream>>>(qkvb, Aaug, Vt, attn_o);

    mgemm<2, 64><<<12 * 77, 256, 0, stream>>>(
        attn_o, wt_proj, proj_b, yb, x, MROWS, DIMC, DIMC, 12, 77);

    ln2_kernel<<<YROWS / 4, 256, 0, stream>>>(yb, ln2_g, ln2_b, h2);

    mgemm<1, 128><<<24 * 64, 256, 0, stream>>>(
        h2, wt_fc1, fc1_b, zb, nullptr, YROWS, MLP_HID, DIMC, 24, 64);

    mgemm<3, 64><<<12 * 64, 256, 0, stream>>>(
        zb, wt_fc2, fc2_b, out, yb, YROWS, DIMC, MLP_HID, 12, 64);
}

// Round 7
// 448.428 us; speedup vs baseline: 8.9159x; 1.0080x over previous
//
#include <hip/hip_runtime.h>
#include <hip/hip_bf16.h>
#include <math.h>

// ---------------------------------------------------------------------------
// Swin/SAM-style block. R7: XOR-swizzled global_load_lds staging in mgemm ->
// conflict-free ds_read_b128 fragment reads (kills the 4.7M conflict cycles).
// ---------------------------------------------------------------------------

#define DIMC 768
#define HEADS 12
#define WIN 14
#define NTOK 196
#define NWIN 50
#define MROWS 9800
#define YROWS 8192
#define MLP_HID 3072

using bf16x8 = __attribute__((ext_vector_type(8))) short;
using f32x4  = __attribute__((ext_vector_type(4))) float;

__device__ __forceinline__ float bf2f(unsigned short u) {
    return __uint_as_float(((unsigned)u) << 16);
}
__device__ __forceinline__ unsigned short f2bf(float f) {
    unsigned u = __float_as_uint(f);
    unsigned r = (u + 0x7fffu + ((u >> 16) & 1u)) >> 16;   // round-nearest-even
    return (unsigned short)r;
}
__device__ __forceinline__ void gl2lds16(const unsigned short* g, unsigned short* l) {
    __builtin_amdgcn_global_load_lds(
        (const __attribute__((address_space(1))) void*)g,
        (__attribute__((address_space(3))) void*)l, 16, 0, 0);
}

// ---------------- tiled weight transpose: W (K x N, f32) -> Wt (N x K, bf16)
__global__ __launch_bounds__(256) void transpose_w(
        const float* __restrict__ W, unsigned short* __restrict__ Wt,
        int K, int N) {
    __shared__ float t[64][65];
    int k0 = blockIdx.y << 6, n0 = blockIdx.x << 6;
    int tn = threadIdx.x & 63;
    int tk = threadIdx.x >> 6;
    #pragma unroll
    for (int r = 0; r < 16; r++) {
        int k = tk + r * 4;
        t[k][tn] = W[(size_t)(k0 + k) * N + n0 + tn];
    }
    __syncthreads();
    #pragma unroll
    for (int r = 0; r < 16; r++) {
        int n = tk + r * 4;
        Wt[(size_t)(n0 + n) * K + k0 + tn] = f2bf(t[tn][n]);
    }
}

// ---------------- LN1 + window partition (zeros in padding) ----------------
__global__ __launch_bounds__(256) void ln1_win_kernel(
        const float* __restrict__ x, const float* __restrict__ g,
        const float* __restrict__ b, unsigned short* __restrict__ h1) {
    int tid = threadIdx.x;
    int row = blockIdx.x * 4 + (tid >> 6);
    int lane = tid & 63;
    if (row >= MROWS) return;
    int w = row / NTOK, t = row % NTOK;
    int bi = w / 25, wr = w % 25;
    int gy = (wr / 5) * WIN + t / WIN;
    int gx = (wr % 5) * WIN + t % WIN;
    unsigned short* out = h1 + (size_t)row * DIMC;
    if (gy >= 64 || gx >= 64) {           // reference pads AFTER LN -> zeros
        #pragma unroll
        for (int j = 0; j < 12; j++) out[lane + 64 * j] = 0;
        return;
    }
    const float* xr = x + ((size_t)((bi * 64 + gy) * 64 + gx)) * DIMC;
    float v[12], s = 0.f;
    #pragma unroll
    for (int j = 0; j < 12; j++) { v[j] = xr[lane + 64 * j]; s += v[j]; }
    #pragma unroll
    for (int o = 32; o > 0; o >>= 1) s += __shfl_xor(s, o);
    float mean = s * (1.f / 768.f);
    float q = 0.f;
    #pragma unroll
    for (int j = 0; j < 12; j++) { float d = v[j] - mean; q += d * d; }
    #pragma unroll
    for (int o = 32; o > 0; o >>= 1) q += __shfl_xor(q, o);
    float inv = rsqrtf(q * (1.f / 768.f) + 1e-6f);
    #pragma unroll
    for (int j = 0; j < 12; j++) {
        int c = lane + 64 * j;
        out[c] = f2bf((v[j] - mean) * inv * g[c] + b[c]);
    }
}

// ---------------- LN2 ----------------
__global__ __launch_bounds__(256) void ln2_kernel(
        const float* __restrict__ y, const float* __restrict__ g,
        const float* __restrict__ b, unsigned short* __restrict__ h2) {
    int tid = threadIdx.x;
    int row = blockIdx.x * 4 + (tid >> 6);
    int lane = tid & 63;
    const float* xr = y + (size_t)row * DIMC;
    float v[12], s = 0.f;
    #pragma unroll
    for (int j = 0; j < 12; j++) { v[j] = xr[lane + 64 * j]; s += v[j]; }
    #pragma unroll
    for (int o = 32; o > 0; o >>= 1) s += __shfl_xor(s, o);
    float mean = s * (1.f / 768.f);
    float q = 0.f;
    #pragma unroll
    for (int j = 0; j < 12; j++) { float d = v[j] - mean; q += d * d; }
    #pragma unroll
    for (int o = 32; o > 0; o >>= 1) q += __shfl_xor(q, o);
    float inv = rsqrtf(q * (1.f / 768.f) + 1e-6f);
    unsigned short* out = h2 + (size_t)row * DIMC;
    #pragma unroll
    for (int j = 0; j < 12; j++) {
        int c = lane + 64 * j;
        out[c] = f2bf((v[j] - mean) * inv * g[c] + b[c]);
    }
}

// ---------------- build A_aug (q | relh | relw | 0) and Vt per (win,head) ----
// rel dots via MFMA: dots[i][r] = q[i] . RT[r], RT = [relph(27) | relpw(27)].
// relh[i][c] = dots[i][13 + i/14 - c]; relw[i][c] = dots[i][27 + 13 + i%14 - c].
__global__ __launch_bounds__(256) void build_aug(
        const unsigned short* __restrict__ qkvb,
        const float* __restrict__ relph, const float* __restrict__ relpw,
        unsigned short* __restrict__ Aaug, unsigned short* __restrict__ Vt) {
    __shared__ unsigned short qs[208 * 72];   // pitch 72: b128-aligned, 2-way banks
    __shared__ unsigned short rt[64 * 72];
    int tid = threadIdx.x;
    int bh = blockIdx.x, w = bh / HEADS, head = bh % HEADS;
    int lane = tid & 63, wave = tid >> 6;
    int l15 = lane & 15, q4 = lane >> 4, q8 = q4 * 8;
    size_t base = (size_t)w * NTOK * 2304 + head * 64;
    unsigned short* ab = Aaug + (size_t)bh * 256 * 96;

    // stage q -> qs, copy to ab cols 0..63
    for (int e = tid; e < 196 * 8; e += 256) {
        int t = e >> 3, s8 = (e & 7) * 8;
        bf16x8 qv = *(const bf16x8*)&qkvb[base + (size_t)t * 2304 + s8];
        *(bf16x8*)&qs[t * 72 + s8] = qv;
        *(bf16x8*)&ab[t * 96 + s8] = qv;
    }
    for (int e = tid; e < 12 * 8; e += 256) {  // zero qs rows 196..207
        bf16x8 z = {};
        *(bf16x8*)&qs[(196 + (e >> 3)) * 72 + (e & 7) * 8] = z;
    }
    // stage RT tables (f32 -> bf16), rows 54..63 zero
    for (int e = tid; e < 64 * 8; e += 256) {
        int r = e >> 3, s8 = (e & 7) * 8;
        bf16x8 ov = {};
        if (r < 54) {
            const float* src = (r < 27 ? relph + (size_t)r * 64
                                       : relpw + (size_t)(r - 27) * 64) + s8;
            #pragma unroll
            for (int jj = 0; jj < 8; jj++) ov[jj] = (short)f2bf(src[jj]);
        }
        *(bf16x8*)&rt[r * 72 + s8] = ov;
    }
    // zero ab rows 196..255 (all 96 cols) and cols 92..95
    for (int e = tid; e < 60 * 12; e += 256) {
        bf16x8 z = {};
        *(bf16x8*)&ab[(size_t)(196 + e / 12) * 96 + (e % 12) * 8] = z;
    }
    for (int e = tid; e < 196; e += 256) {
        ab[e * 96 + 92] = 0; ab[e * 96 + 93] = 0;
        ab[e * 96 + 94] = 0; ab[e * 96 + 95] = 0;
    }
    __syncthreads();

    // rel MFMA + scatter into ab cols 64..91
    #pragma unroll
    for (int t = 0; t < 4; t++) {
        int it = wave * 4 + t;
        if (it >= 13) break;                      // wave-uniform
        bf16x8 a0 = *(bf16x8*)&qs[(it * 16 + l15) * 72 + q8];
        bf16x8 a1 = *(bf16x8*)&qs[(it * 16 + l15) * 72 + 32 + q8];
        #pragma unroll
        for (int rt4 = 0; rt4 < 4; rt4++) {
            bf16x8 b0 = *(bf16x8*)&rt[(rt4 * 16 + l15) * 72 + q8];
            bf16x8 b1 = *(bf16x8*)&rt[(rt4 * 16 + l15) * 72 + 32 + q8];
            f32x4 d4 = {};
            d4 = __builtin_amdgcn_mfma_f32_16x16x32_bf16(a0, b0, d4, 0, 0, 0);
            d4 = __builtin_amdgcn_mfma_f32_16x16x32_bf16(a1, b1, d4, 0, 0, 0);
            int rcol = rt4 * 16 + l15;
            #pragma unroll
            for (int r = 0; r < 4; r++) {
                int i = it * 16 + q4 * 4 + r;
                if (i < 196 && rcol < 54) {
                    if (rcol < 27) {
                        int c = 13 + i / 14 - rcol;
                        if (c >= 0 && c < 14) ab[i * 96 + 64 + c] = f2bf(d4[r]);
                    } else {
                        int c = 13 + i % 14 - (rcol - 27);
                        if (c >= 0 && c < 14) ab[i * 96 + 78 + c] = f2bf(d4[r]);
                    }
                }
            }
        }
    }

    // Vt[d][224]: vector read V, scalar global scatter (L2 write-combines)
    unsigned short* vtb = Vt + (size_t)bh * 64 * 224;
    for (int e = tid; e < 196 * 8; e += 256) {
        int j = e >> 3, dg = (e & 7) * 8;
        bf16x8 vv = *(const bf16x8*)&qkvb[base + 1536 + (size_t)j * 2304 + dg];
        #pragma unroll
        for (int k = 0; k < 8; k++)
            vtb[(size_t)(dg + k) * 224 + j] = (unsigned short)vv[k];
    }
    for (int e = tid; e < 64 * 28; e += 256)     // zero cols 196..223
        vtb[(size_t)(e / 28) * 224 + 196 + (e % 28)] = 0;
}

// ---------------- fused MFMA attention: one block per (window,head) --------
__global__ __launch_bounds__(256) void attn_mfma(
        const unsigned short* __restrict__ qkvb,
        const unsigned short* __restrict__ Aaug,
        const unsigned short* __restrict__ Vt,
        unsigned short* __restrict__ out) {
    __shared__ unsigned short Kls[208 * 96];   // K_aug: [k*0.125 | oh(j/14) | oh(j%14) | 0]
    __shared__ unsigned short Pls[4][64 * 40]; // per-wave P strip, pitch 40
    int tid = threadIdx.x;
    int bh = blockIdx.x, w = bh / HEADS, head = bh % HEADS;
    int wave = tid >> 6, lane = tid & 63;
    int l15 = lane & 15, q4 = lane >> 4, q8 = q4 * 8;
    size_t kbase = (size_t)w * NTOK * 2304 + head * 64 + 768;
    // stage K*0.125 (exact: pow2) rows 0..195
    for (int e = tid; e < 196 * 8; e += 256) {
        int t = e >> 3, s8 = (e & 7) * 8;
        bf16x8 kv = *(const bf16x8*)&qkvb[kbase + (size_t)t * 2304 + s8];
        bf16x8 ko;
        #pragma unroll
        for (int jj = 0; jj < 8; jj++)
            ko[jj] = (short)f2bf(bf2f((unsigned short)kv[jj]) * 0.125f);
        *(bf16x8*)&Kls[t * 96 + s8] = ko;
    }
    bf16x8 z8 = {};
    for (int e = tid; e < 208 * 4; e += 256)   // zero cols 64..95
        *(bf16x8*)&Kls[(e >> 2) * 96 + 64 + (e & 3) * 8] = z8;
    for (int e = tid; e < 12 * 8; e += 256)    // zero rows 196..207 cols 0..63
        *(bf16x8*)&Kls[(196 + (e >> 3)) * 96 + (e & 7) * 8] = z8;
    __syncthreads();                           // zeros before one-hots (same dwords)
    for (int e = tid; e < 196; e += 256) {
        Kls[e * 96 + 64 + e / WIN] = 0x3F80;   // bf16(1.0)
        Kls[e * 96 + 78 + e % WIN] = 0x3F80;
    }
    // A-frags from global (held in regs across all j-tiles)
    bf16x8 af[4][3];
    const unsigned short* abse = Aaug + (size_t)bh * 256 * 96;
    #pragma unroll
    for (int it = 0; it < 4; it++)
        #pragma unroll
        for (int c = 0; c < 3; c++)
            af[it][c] = *(const bf16x8*)&abse[(size_t)(wave * 64 + it * 16 + l15) * 96 + c * 32 + q8];
    __syncthreads();                           // K_aug complete

    const unsigned short* vtb = Vt + (size_t)bh * 64 * 224;
    f32x4 o[4][4] = {};
    float lacc[4][4] = {{0.f}};
    bf16x8 bv[4];
    #pragma unroll
    for (int dt = 0; dt < 4; dt++)
        bv[dt] = *(const bf16x8*)&vtb[(dt * 16 + l15) * 224 + q8];

    for (int jp = 0; jp < 7; jp++) {
        f32x4 s[4][2] = {};
        #pragma unroll
        for (int half = 0; half < 2; half++) {
            int jt = jp * 2 + half;
            if (jt < 13) {
                #pragma unroll
                for (int c = 0; c < 3; c++) {
                    bf16x8 bk = *(bf16x8*)&Kls[(jt * 16 + l15) * 96 + c * 32 + q8];
                    #pragma unroll
                    for (int it = 0; it < 4; it++)
                        s[it][half] = __builtin_amdgcn_mfma_f32_16x16x32_bf16(
                            af[it][c], bk, s[it][half], 0, 0, 0);
                }
            }
        }
        __syncthreads();   // WAR: previous PV reads of Pls complete
        #pragma unroll
        for (int half = 0; half < 2; half++) {
            int jt = jp * 2 + half;
            bool valid = (jt < 13) && (jt * 16 + l15) < 196;
            #pragma unroll
            for (int it = 0; it < 4; it++)
                #pragma unroll
                for (int r = 0; r < 4; r++) {
                    float p = valid ? __expf(s[it][half][r]) : 0.f;
                    unsigned short pb = f2bf(p);
                    lacc[it][r] += bf2f(pb);
                    Pls[wave][(it * 16 + q4 * 4 + r) * 40 + half * 16 + l15] = pb;
                }
        }
        __syncthreads();   // RAW: P visible
        bf16x8 ap[4];
        #pragma unroll
        for (int it = 0; it < 4; it++)
            ap[it] = *(bf16x8*)&Pls[wave][(it * 16 + l15) * 40 + q8];
        bf16x8 bvn[4];
        if (jp < 6) {
            #pragma unroll
            for (int dt = 0; dt < 4; dt++)
                bvn[dt] = *(const bf16x8*)&vtb[(dt * 16 + l15) * 224 + (jp + 1) * 32 + q8];
        }
        #pragma unroll
        for (int dt = 0; dt < 4; dt++)
            #pragma unroll
            for (int it = 0; it < 4; it++)
                o[it][dt] = __builtin_amdgcn_mfma_f32_16x16x32_bf16(
                    ap[it], bv[dt], o[it][dt], 0, 0, 0);
        if (jp < 6) {
            #pragma unroll
            for (int dt = 0; dt < 4; dt++) bv[dt] = bvn[dt];
        }
    }
    // row sums across the 16 j-lanes of each quad
    #pragma unroll
    for (int it = 0; it < 4; it++)
        #pragma unroll
        for (int r = 0; r < 4; r++) {
            float v = lacc[it][r];
            v += __shfl_xor(v, 1); v += __shfl_xor(v, 2);
            v += __shfl_xor(v, 4); v += __shfl_xor(v, 8);
            lacc[it][r] = 1.f / v;
        }
    // store O (win, token, head, d)
    #pragma unroll
    for (int it = 0; it < 4; it++) {
        int i0 = wave * 64 + it * 16 + q4 * 4;
        #pragma unroll
        for (int r = 0; r < 4; r++) {
            if (i0 + r < 196) {
                size_t rowb = (size_t)(w * NTOK + i0 + r) * DIMC + head * 64;
                #pragma unroll
                for (int dt = 0; dt < 4; dt++)
                    out[rowb + dt * 16 + l15] = f2bf(o[it][dt][r] * lacc[it][r]);
            }
        }
    }
}

// ---------------- MFMA GEMM (m97 + XCD swizzle + XOR-swizzled LDS): ---------
// C = A(MxK bf16) @ Bt(NxK bf16)^T + bias.  BM=128, BN in {128,64}, BK=32.
// Staging: lane reads global 16B-seg ((lane&3)^((lane>>3)&3)) of its row;
// frag reads use seg (q4^((l15>>1)&3)) -> all 8 LDS bank-groups hit per
// 8-lane phase -> conflict-free ds_read_b128. Global reads stay 64B-coalesced.
// EPI 0: bf16 store   EPI 1: exact gelu -> bf16
// EPI 2: window-unpartition + x residual (f32)   EPI 3: + resid (f32)
template <int EPI, int BN>
__global__ __launch_bounds__(256) void mgemm(
        const unsigned short* __restrict__ A, const unsigned short* __restrict__ Bt,
        const float* __restrict__ bias, void* __restrict__ Cout,
        const float* __restrict__ resid, int M, int Nn, int K,
        int nbx, int nby) {
    const int NI = BN / 32;                 // per-wave n-frags
    __shared__ unsigned short As[128 * 32];
    __shared__ unsigned short Bs[BN * 32];
    int tid = threadIdx.x;
    int lane = tid & 63, wave = tid >> 6;
    int l15 = lane & 15, q4 = lane >> 4;
    int xq8 = (q4 ^ ((l15 >> 1) & 3)) * 8;  // swizzled frag segment (shorts)
    // ---- XCD swizzle ----
    int id = blockIdx.x;
    int per = nbx * 8;
    int s = id / per;
    int rem = id - s * per;
    int rmax = nby - s * 8; if (rmax > 8) rmax = 8;
    int bx = rem / rmax;
    int r_ = rem - bx * rmax;
    int by = s * 8 + r_;
    int m0 = by << 7, n0 = bx * BN;
    int wm = (wave >> 1) * 64, wn = (wave & 1) * (BN / 2);
    // staging: lane i -> row i/4, swizzled global seg; LDS dst = base + lane*16
    int srow0 = wave * 32 + (lane >> 2);
    int srow1 = srow0 + 16;
    int sseg = ((lane & 3) ^ ((lane >> 3) & 3)) * 8;   // shorts
    int rmA0 = m0 + srow0; if (rmA0 >= M) rmA0 = M - 1;   // clamp: rows>=M never stored
    int rmA1 = m0 + srow1; if (rmA1 >= M) rmA1 = M - 1;
    const unsigned short* gA0 = A + (size_t)rmA0 * K + sseg;
    const unsigned short* gA1 = A + (size_t)rmA1 * K + sseg;
    unsigned short* lA0 = As + wave * 1024 + lane * 8;
    unsigned short* lA1 = lA0 + 512;
    int browB = (BN == 128) ? srow0 : (wave * 16 + (lane >> 2));
    const unsigned short* gB0 = Bt + (size_t)(n0 + browB) * K + sseg;
    const unsigned short* gB1 = Bt + (size_t)(n0 + srow1) * K + sseg;  // BN=128 only
    unsigned short* lB0 = Bs + ((BN == 128) ? wave * 1024 : wave * 512) + lane * 8;
    unsigned short* lB1 = lB0 + 512;
    f32x4 acc[4][NI] = {};
    for (int k0 = 0; k0 < K; k0 += 32) {
        gl2lds16(gA0 + k0, lA0);
        gl2lds16(gA1 + k0, lA1);
        gl2lds16(gB0 + k0, lB0);
        if (BN == 128) gl2lds16(gB1 + k0, lB1);
        __syncthreads();                     // drains vmcnt + barrier
        bf16x8 bfr[NI];
        #pragma unroll
        for (int ni = 0; ni < NI; ni++)
            bfr[ni] = *(bf16x8*)&Bs[(wn + ni * 16 + l15) * 32 + xq8];
        #pragma unroll
        for (int mi = 0; mi < 4; mi++) {
            bf16x8 afr = *(bf16x8*)&As[(wm + mi * 16 + l15) * 32 + xq8];
            #pragma unroll
            for (int ni = 0; ni < NI; ni++)
                acc[mi][ni] = __builtin_amdgcn_mfma_f32_16x16x32_bf16(
                    afr, bfr[ni], acc[mi][ni], 0, 0, 0);
        }
        __syncthreads();
    }
    int q4r = (lane >> 4) * 4;
    #pragma unroll
    for (int mi = 0; mi < 4; mi++) {
        #pragma unroll
        for (int r = 0; r < 4; r++) {
            int row = m0 + wm + mi * 16 + q4r + r;
            if (row >= M) continue;
            if (EPI == 2) {
                int w = row / NTOK, t = row % NTOK;
                int bi = w / 25, wr = w % 25;
                int gy = (wr / 5) * WIN + t / WIN;
                int gx = (wr % 5) * WIN + t % WIN;
                if (gy >= 64 || gx >= 64) continue;
                size_t orow = ((size_t)((bi * 64 + gy) * 64 + gx)) * DIMC;
                #pragma unroll
                for (int ni = 0; ni < NI; ni++) {
                    int col = n0 + wn + ni * 16 + l15;
                    float v = acc[mi][ni][r] + bias[col];
                    ((float*)Cout)[orow + col] = resid[orow + col] + v;
                }
            } else {
                #pragma unroll
                for (int ni = 0; ni < NI; ni++) {
                    int col = n0 + wn + ni * 16 + l15;
                    float v = acc[mi][ni][r] + bias[col];
                    if (EPI == 0) {
                        ((unsigned short*)Cout)[(size_t)row * Nn + col] = f2bf(v);
                    } else if (EPI == 1) {
                        v = 0.5f * v * (1.f + erff(v * 0.70710678118654752f));
                        ((unsigned short*)Cout)[(size_t)row * Nn + col] = f2bf(v);
                    } else {
                        ((float*)Cout)[(size_t)row * Nn + col] =
                            resid[(size_t)row * Nn + col] + v;
                    }
                }
            }
        }
    }
}

// ---------------------------------------------------------------------------
extern "C" void kernel_launch(void* const* d_in, const int* in_sizes, int n_in,
                              void* d_out, int out_size, void* d_ws, size_t ws_size,
                              hipStream_t stream) {
    const float* x      = (const float*)d_in[0];
    const float* ln1_g  = (const float*)d_in[1];
    const float* ln1_b  = (const float*)d_in[2];
    const float* qkv_w  = (const float*)d_in[3];
    const float* qkv_b  = (const float*)d_in[4];
    const float* proj_w = (const float*)d_in[5];
    const float* proj_b = (const float*)d_in[6];
    const float* rel_h  = (const float*)d_in[7];
    const float* rel_w  = (const float*)d_in[8];
    const float* ln2_g  = (const float*)d_in[9];
    const float* ln2_b  = (const float*)d_in[10];
    const float* fc1_w  = (const float*)d_in[11];
    const float* fc1_b  = (const float*)d_in[12];
    const float* fc2_w  = (const float*)d_in[13];
    const float* fc2_b  = (const float*)d_in[14];
    float* out = (float*)d_out;
    char* ws = (char*)d_ws;

    // Workspace regions (max 121,061,376 B), liveness-checked (same as R3-R6):
    unsigned short* wt_qkv  = (unsigned short*)(ws);
    unsigned short* wt_proj = (unsigned short*)(ws + 3538944);
    unsigned short* wt_fc1  = (unsigned short*)(ws + 4718592);
    unsigned short* wt_fc2  = (unsigned short*)(ws + 9437184);
    unsigned short* qkvb    = (unsigned short*)(ws + 14155776);
    float*          yb      = (float*)        (ws + 14155776);
    unsigned short* h2      = (unsigned short*)(ws + 39321600);
    unsigned short* h1      = (unsigned short*)(ws + 59314176);
    unsigned short* attn_o  = h1;
    unsigned short* zb      = h1;
    unsigned short* Aaug    = (unsigned short*)(ws + 74366976);
    unsigned short* Vt      = (unsigned short*)(ws + 103858176);

    transpose_w<<<dim3(36, 12), 256, 0, stream>>>(qkv_w,  wt_qkv,  768, 2304);
    transpose_w<<<dim3(12, 12), 256, 0, stream>>>(proj_w, wt_proj, 768, 768);
    transpose_w<<<dim3(48, 12), 256, 0, stream>>>(fc1_w,  wt_fc1,  768, 3072);
    transpose_w<<<dim3(12, 48), 256, 0, stream>>>(fc2_w,  wt_fc2,  3072, 768);

    ln1_win_kernel<<<(MROWS + 3) / 4, 256, 0, stream>>>(x, ln1_g, ln1_b, h1);

    mgemm<0, 128><<<18 * 77, 256, 0, stream>>>(
        h1, wt_qkv, qkv_b, qkvb, nullptr, MROWS, 2304, DIMC, 18, 77);

    build_aug<<<NWIN * HEADS, 256, 0, stream>>>(qkvb, rel_h, rel_w, Aaug, Vt);

    attn_mfma<<<NWIN * HEADS, 256, 0, stream>>>(qkvb, Aaug, Vt, attn_o);

    mgemm<2, 64><<<12 * 77, 256, 0, stream>>>(
        attn_o, wt_proj, proj_b, yb, x, MROWS, DIMC, DIMC, 12, 77);

    ln2_kernel<<<YROWS / 4, 256, 0, stream>>>(yb, ln2_g, ln2_b, h2);

    mgemm<1, 128><<<24 * 64, 256, 0, stream>>>(
        h2, wt_fc1, fc1_b, zb, nullptr, YROWS, MLP_HID, DIMC, 24, 64);

    mgemm<3, 64><<<12 * 64, 256, 0, stream>>>(
        zb, wt_fc2, fc2_b, out, yb, YROWS, DIMC, MLP_HID, 12, 64);
}

// Round 8
// 442.456 us; speedup vs baseline: 9.0363x; 1.0135x over previous
//
#include <hip/hip_runtime.h>
#include <hip/hip_bf16.h>
#include <math.h>

// ---------------------------------------------------------------------------
// Swin/SAM-style block. R8: ping-pong double-buffered LDS in mgemm (hide
// L3-latency staging behind MFMA compute); merge 4 weight-transposes into 1.
// ---------------------------------------------------------------------------

#define DIMC 768
#define HEADS 12
#define WIN 14
#define NTOK 196
#define NWIN 50
#define MROWS 9800
#define YROWS 8192
#define MLP_HID 3072

using bf16x8 = __attribute__((ext_vector_type(8))) short;
using f32x4  = __attribute__((ext_vector_type(4))) float;

__device__ __forceinline__ float bf2f(unsigned short u) {
    return __uint_as_float(((unsigned)u) << 16);
}
__device__ __forceinline__ unsigned short f2bf(float f) {
    unsigned u = __float_as_uint(f);
    unsigned r = (u + 0x7fffu + ((u >> 16) & 1u)) >> 16;   // round-nearest-even
    return (unsigned short)r;
}
__device__ __forceinline__ void gl2lds16(const unsigned short* g, unsigned short* l) {
    __builtin_amdgcn_global_load_lds(
        (const __attribute__((address_space(1))) void*)g,
        (__attribute__((address_space(3))) void*)l, 16, 0, 0);
}

// ---------------- fused 4-way weight transpose: W (K x N, f32) -> Wt (N x K, bf16)
// block ranges: [0,432) qkv  [432,576) proj  [576,1152) fc1  [1152,1728) fc2
__global__ __launch_bounds__(256) void transpose_all(
        const float* __restrict__ Wq, unsigned short* __restrict__ Tq,
        const float* __restrict__ Wp, unsigned short* __restrict__ Tp,
        const float* __restrict__ W1, unsigned short* __restrict__ T1,
        const float* __restrict__ W2, unsigned short* __restrict__ T2) {
    int id = blockIdx.x;
    const float* W; unsigned short* Wt; int K, N, nbx, rel;
    if (id < 432)       { W = Wq; Wt = Tq; K = 768;  N = 2304; nbx = 36; rel = id; }
    else if (id < 576)  { W = Wp; Wt = Tp; K = 768;  N = 768;  nbx = 12; rel = id - 432; }
    else if (id < 1152) { W = W1; Wt = T1; K = 768;  N = 3072; nbx = 48; rel = id - 576; }
    else                { W = W2; Wt = T2; K = 3072; N = 768;  nbx = 12; rel = id - 1152; }
    int bx = rel % nbx, by = rel / nbx;
    __shared__ float t[64][65];
    int k0 = by << 6, n0 = bx << 6;
    int tn = threadIdx.x & 63;
    int tk = threadIdx.x >> 6;
    #pragma unroll
    for (int r = 0; r < 16; r++) {
        int k = tk + r * 4;
        t[k][tn] = W[(size_t)(k0 + k) * N + n0 + tn];
    }
    __syncthreads();
    #pragma unroll
    for (int r = 0; r < 16; r++) {
        int n = tk + r * 4;
        Wt[(size_t)(n0 + n) * K + k0 + tn] = f2bf(t[tn][n]);
    }
}

// ---------------- LN1 + window partition (zeros in padding) ----------------
__global__ __launch_bounds__(256) void ln1_win_kernel(
        const float* __restrict__ x, const float* __restrict__ g,
        const float* __restrict__ b, unsigned short* __restrict__ h1) {
    int tid = threadIdx.x;
    int row = blockIdx.x * 4 + (tid >> 6);
    int lane = tid & 63;
    if (row >= MROWS) return;
    int w = row / NTOK, t = row % NTOK;
    int bi = w / 25, wr = w % 25;
    int gy = (wr / 5) * WIN + t / WIN;
    int gx = (wr % 5) * WIN + t % WIN;
    unsigned short* out = h1 + (size_t)row * DIMC;
    if (gy >= 64 || gx >= 64) {           // reference pads AFTER LN -> zeros
        #pragma unroll
        for (int j = 0; j < 12; j++) out[lane + 64 * j] = 0;
        return;
    }
    const float* xr = x + ((size_t)((bi * 64 + gy) * 64 + gx)) * DIMC;
    float v[12], s = 0.f;
    #pragma unroll
    for (int j = 0; j < 12; j++) { v[j] = xr[lane + 64 * j]; s += v[j]; }
    #pragma unroll
    for (int o = 32; o > 0; o >>= 1) s += __shfl_xor(s, o);
    float mean = s * (1.f / 768.f);
    float q = 0.f;
    #pragma unroll
    for (int j = 0; j < 12; j++) { float d = v[j] - mean; q += d * d; }
    #pragma unroll
    for (int o = 32; o > 0; o >>= 1) q += __shfl_xor(q, o);
    float inv = rsqrtf(q * (1.f / 768.f) + 1e-6f);
    #pragma unroll
    for (int j = 0; j < 12; j++) {
        int c = lane + 64 * j;
        out[c] = f2bf((v[j] - mean) * inv * g[c] + b[c]);
    }
}

// ---------------- LN2 ----------------
__global__ __launch_bounds__(256) void ln2_kernel(
        const float* __restrict__ y, const float* __restrict__ g,
        const float* __restrict__ b, unsigned short* __restrict__ h2) {
    int tid = threadIdx.x;
    int row = blockIdx.x * 4 + (tid >> 6);
    int lane = tid & 63;
    const float* xr = y + (size_t)row * DIMC;
    float v[12], s = 0.f;
    #pragma unroll
    for (int j = 0; j < 12; j++) { v[j] = xr[lane + 64 * j]; s += v[j]; }
    #pragma unroll
    for (int o = 32; o > 0; o >>= 1) s += __shfl_xor(s, o);
    float mean = s * (1.f / 768.f);
    float q = 0.f;
    #pragma unroll
    for (int j = 0; j < 12; j++) { float d = v[j] - mean; q += d * d; }
    #pragma unroll
    for (int o = 32; o > 0; o >>= 1) q += __shfl_xor(q, o);
    float inv = rsqrtf(q * (1.f / 768.f) + 1e-6f);
    unsigned short* out = h2 + (size_t)row * DIMC;
    #pragma unroll
    for (int j = 0; j < 12; j++) {
        int c = lane + 64 * j;
        out[c] = f2bf((v[j] - mean) * inv * g[c] + b[c]);
    }
}

// ---------------- build A_aug (q | relh | relw | 0) and Vt per (win,head) ----
// rel dots via MFMA: dots[i][r] = q[i] . RT[r], RT = [relph(27) | relpw(27)].
// relh[i][c] = dots[i][13 + i/14 - c]; relw[i][c] = dots[i][27 + 13 + i%14 - c].
__global__ __launch_bounds__(256) void build_aug(
        const unsigned short* __restrict__ qkvb,
        const float* __restrict__ relph, const float* __restrict__ relpw,
        unsigned short* __restrict__ Aaug, unsigned short* __restrict__ Vt) {
    __shared__ unsigned short qs[208 * 72];   // pitch 72: b128-aligned, 2-way banks
    __shared__ unsigned short rt[64 * 72];
    int tid = threadIdx.x;
    int bh = blockIdx.x, w = bh / HEADS, head = bh % HEADS;
    int lane = tid & 63, wave = tid >> 6;
    int l15 = lane & 15, q4 = lane >> 4, q8 = q4 * 8;
    size_t base = (size_t)w * NTOK * 2304 + head * 64;
    unsigned short* ab = Aaug + (size_t)bh * 256 * 96;

    // stage q -> qs, copy to ab cols 0..63
    for (int e = tid; e < 196 * 8; e += 256) {
        int t = e >> 3, s8 = (e & 7) * 8;
        bf16x8 qv = *(const bf16x8*)&qkvb[base + (size_t)t * 2304 + s8];
        *(bf16x8*)&qs[t * 72 + s8] = qv;
        *(bf16x8*)&ab[t * 96 + s8] = qv;
    }
    for (int e = tid; e < 12 * 8; e += 256) {  // zero qs rows 196..207
        bf16x8 z = {};
        *(bf16x8*)&qs[(196 + (e >> 3)) * 72 + (e & 7) * 8] = z;
    }
    // stage RT tables (f32 -> bf16), rows 54..63 zero
    for (int e = tid; e < 64 * 8; e += 256) {
        int r = e >> 3, s8 = (e & 7) * 8;
        bf16x8 ov = {};
        if (r < 54) {
            const float* src = (r < 27 ? relph + (size_t)r * 64
                                       : relpw + (size_t)(r - 27) * 64) + s8;
            #pragma unroll
            for (int jj = 0; jj < 8; jj++) ov[jj] = (short)f2bf(src[jj]);
        }
        *(bf16x8*)&rt[r * 72 + s8] = ov;
    }
    // zero ab rows 196..255 (all 96 cols) and cols 92..95
    for (int e = tid; e < 60 * 12; e += 256) {
        bf16x8 z = {};
        *(bf16x8*)&ab[(size_t)(196 + e / 12) * 96 + (e % 12) * 8] = z;
    }
    for (int e = tid; e < 196; e += 256) {
        ab[e * 96 + 92] = 0; ab[e * 96 + 93] = 0;
        ab[e * 96 + 94] = 0; ab[e * 96 + 95] = 0;
    }
    __syncthreads();

    // rel MFMA + scatter into ab cols 64..91
    #pragma unroll
    for (int t = 0; t < 4; t++) {
        int it = wave * 4 + t;
        if (it >= 13) break;                      // wave-uniform
        bf16x8 a0 = *(bf16x8*)&qs[(it * 16 + l15) * 72 + q8];
        bf16x8 a1 = *(bf16x8*)&qs[(it * 16 + l15) * 72 + 32 + q8];
        #pragma unroll
        for (int rt4 = 0; rt4 < 4; rt4++) {
            bf16x8 b0 = *(bf16x8*)&rt[(rt4 * 16 + l15) * 72 + q8];
            bf16x8 b1 = *(bf16x8*)&rt[(rt4 * 16 + l15) * 72 + 32 + q8];
            f32x4 d4 = {};
            d4 = __builtin_amdgcn_mfma_f32_16x16x32_bf16(a0, b0, d4, 0, 0, 0);
            d4 = __builtin_amdgcn_mfma_f32_16x16x32_bf16(a1, b1, d4, 0, 0, 0);
            int rcol = rt4 * 16 + l15;
            #pragma unroll
            for (int r = 0; r < 4; r++) {
                int i = it * 16 + q4 * 4 + r;
                if (i < 196 && rcol < 54) {
                    if (rcol < 27) {
                        int c = 13 + i / 14 - rcol;
                        if (c >= 0 && c < 14) ab[i * 96 + 64 + c] = f2bf(d4[r]);
                    } else {
                        int c = 13 + i % 14 - (rcol - 27);
                        if (c >= 0 && c < 14) ab[i * 96 + 78 + c] = f2bf(d4[r]);
                    }
                }
            }
        }
    }

    // Vt[d][224]: vector read V, scalar global scatter (L2 write-combines)
    unsigned short* vtb = Vt + (size_t)bh * 64 * 224;
    for (int e = tid; e < 196 * 8; e += 256) {
        int j = e >> 3, dg = (e & 7) * 8;
        bf16x8 vv = *(const bf16x8*)&qkvb[base + 1536 + (size_t)j * 2304 + dg];
        #pragma unroll
        for (int k = 0; k < 8; k++)
            vtb[(size_t)(dg + k) * 224 + j] = (unsigned short)vv[k];
    }
    for (int e = tid; e < 64 * 28; e += 256)     // zero cols 196..223
        vtb[(size_t)(e / 28) * 224 + 196 + (e % 28)] = 0;
}

// ---------------- fused MFMA attention: one block per (window,head) --------
__global__ __launch_bounds__(256) void attn_mfma(
        const unsigned short* __restrict__ qkvb,
        const unsigned short* __restrict__ Aaug,
        const unsigned short* __restrict__ Vt,
        unsigned short* __restrict__ out) {
    __shared__ unsigned short Kls[208 * 96];   // K_aug: [k*0.125 | oh(j/14) | oh(j%14) | 0]
    __shared__ unsigned short Pls[4][64 * 40]; // per-wave P strip, pitch 40
    int tid = threadIdx.x;
    int bh = blockIdx.x, w = bh / HEADS, head = bh % HEADS;
    int wave = tid >> 6, lane = tid & 63;
    int l15 = lane & 15, q4 = lane >> 4, q8 = q4 * 8;
    size_t kbase = (size_t)w * NTOK * 2304 + head * 64 + 768;
    // stage K*0.125 (exact: pow2) rows 0..195
    for (int e = tid; e < 196 * 8; e += 256) {
        int t = e >> 3, s8 = (e & 7) * 8;
        bf16x8 kv = *(const bf16x8*)&qkvb[kbase + (size_t)t * 2304 + s8];
        bf16x8 ko;
        #pragma unroll
        for (int jj = 0; jj < 8; jj++)
            ko[jj] = (short)f2bf(bf2f((unsigned short)kv[jj]) * 0.125f);
        *(bf16x8*)&Kls[t * 96 + s8] = ko;
    }
    bf16x8 z8 = {};
    for (int e = tid; e < 208 * 4; e += 256)   // zero cols 64..95
        *(bf16x8*)&Kls[(e >> 2) * 96 + 64 + (e & 3) * 8] = z8;
    for (int e = tid; e < 12 * 8; e += 256)    // zero rows 196..207 cols 0..63
        *(bf16x8*)&Kls[(196 + (e >> 3)) * 96 + (e & 7) * 8] = z8;
    __syncthreads();                           // zeros before one-hots (same dwords)
    for (int e = tid; e < 196; e += 256) {
        Kls[e * 96 + 64 + e / WIN] = 0x3F80;   // bf16(1.0)
        Kls[e * 96 + 78 + e % WIN] = 0x3F80;
    }
    // A-frags from global (held in regs across all j-tiles)
    bf16x8 af[4][3];
    const unsigned short* abse = Aaug + (size_t)bh * 256 * 96;
    #pragma unroll
    for (int it = 0; it < 4; it++)
        #pragma unroll
        for (int c = 0; c < 3; c++)
            af[it][c] = *(const bf16x8*)&abse[(size_t)(wave * 64 + it * 16 + l15) * 96 + c * 32 + q8];
    __syncthreads();                           // K_aug complete

    const unsigned short* vtb = Vt + (size_t)bh * 64 * 224;
    f32x4 o[4][4] = {};
    float lacc[4][4] = {{0.f}};
    bf16x8 bv[4];
    #pragma unroll
    for (int dt = 0; dt < 4; dt++)
        bv[dt] = *(const bf16x8*)&vtb[(dt * 16 + l15) * 224 + q8];

    for (int jp = 0; jp < 7; jp++) {
        f32x4 s[4][2] = {};
        #pragma unroll
        for (int half = 0; half < 2; half++) {
            int jt = jp * 2 + half;
            if (jt < 13) {
                #pragma unroll
                for (int c = 0; c < 3; c++) {
                    bf16x8 bk = *(bf16x8*)&Kls[(jt * 16 + l15) * 96 + c * 32 + q8];
                    #pragma unroll
                    for (int it = 0; it < 4; it++)
                        s[it][half] = __builtin_amdgcn_mfma_f32_16x16x32_bf16(
                            af[it][c], bk, s[it][half], 0, 0, 0);
                }
            }
        }
        __syncthreads();   // WAR: previous PV reads of Pls complete
        #pragma unroll
        for (int half = 0; half < 2; half++) {
            int jt = jp * 2 + half;
            bool valid = (jt < 13) && (jt * 16 + l15) < 196;
            #pragma unroll
            for (int it = 0; it < 4; it++)
                #pragma unroll
                for (int r = 0; r < 4; r++) {
                    float p = valid ? __expf(s[it][half][r]) : 0.f;
                    unsigned short pb = f2bf(p);
                    lacc[it][r] += bf2f(pb);
                    Pls[wave][(it * 16 + q4 * 4 + r) * 40 + half * 16 + l15] = pb;
                }
        }
        __syncthreads();   // RAW: P visible
        bf16x8 ap[4];
        #pragma unroll
        for (int it = 0; it < 4; it++)
            ap[it] = *(bf16x8*)&Pls[wave][(it * 16 + l15) * 40 + q8];
        bf16x8 bvn[4];
        if (jp < 6) {
            #pragma unroll
            for (int dt = 0; dt < 4; dt++)
                bvn[dt] = *(const bf16x8*)&vtb[(dt * 16 + l15) * 224 + (jp + 1) * 32 + q8];
        }
        #pragma unroll
        for (int dt = 0; dt < 4; dt++)
            #pragma unroll
            for (int it = 0; it < 4; it++)
                o[it][dt] = __builtin_amdgcn_mfma_f32_16x16x32_bf16(
                    ap[it], bv[dt], o[it][dt], 0, 0, 0);
        if (jp < 6) {
            #pragma unroll
            for (int dt = 0; dt < 4; dt++) bv[dt] = bvn[dt];
        }
    }
    // row sums across the 16 j-lanes of each quad
    #pragma unroll
    for (int it = 0; it < 4; it++)
        #pragma unroll
        for (int r = 0; r < 4; r++) {
            float v = lacc[it][r];
            v += __shfl_xor(v, 1); v += __shfl_xor(v, 2);
            v += __shfl_xor(v, 4); v += __shfl_xor(v, 8);
            lacc[it][r] = 1.f / v;
        }
    // store O (win, token, head, d)
    #pragma unroll
    for (int it = 0; it < 4; it++) {
        int i0 = wave * 64 + it * 16 + q4 * 4;
        #pragma unroll
        for (int r = 0; r < 4; r++) {
            if (i0 + r < 196) {
                size_t rowb = (size_t)(w * NTOK + i0 + r) * DIMC + head * 64;
                #pragma unroll
                for (int dt = 0; dt < 4; dt++)
                    out[rowb + dt * 16 + l15] = f2bf(o[it][dt][r] * lacc[it][r]);
            }
        }
    }
}

// ---------------- MFMA GEMM (ping-pong dbuf + XCD swizzle + XOR LDS): -------
// C = A(MxK bf16) @ Bt(NxK bf16)^T + bias.  BM=128, BN in {128,64}, BK=32.
// Per iter: sync (drain prev loads) -> issue next-tile loads into buf^1 ->
// compute from buf (loads fly during compute; next sync drains them).
// EPI 0: bf16 store   EPI 1: exact gelu -> bf16
// EPI 2: window-unpartition + x residual (f32)   EPI 3: + resid (f32)
template <int EPI, int BN>
__global__ __launch_bounds__(256) void mgemm(
        const unsigned short* __restrict__ A, const unsigned short* __restrict__ Bt,
        const float* __restrict__ bias, void* __restrict__ Cout,
        const float* __restrict__ resid, int M, int Nn, int K,
        int nbx, int nby) {
    const int NI = BN / 32;                 // per-wave n-frags
    __shared__ unsigned short As[2][128 * 32];
    __shared__ unsigned short Bs[2][BN * 32];
    int tid = threadIdx.x;
    int lane = tid & 63, wave = tid >> 6;
    int l15 = lane & 15, q4 = lane >> 4;
    int xq8 = (q4 ^ ((l15 >> 1) & 3)) * 8;  // swizzled frag segment (shorts)
    // ---- XCD swizzle ----
    int id = blockIdx.x;
    int per = nbx * 8;
    int s = id / per;
    int rem = id - s * per;
    int rmax = nby - s * 8; if (rmax > 8) rmax = 8;
    int bx = rem / rmax;
    int r_ = rem - bx * rmax;
    int by = s * 8 + r_;
    int m0 = by << 7, n0 = bx * BN;
    int wm = (wave >> 1) * 64, wn = (wave & 1) * (BN / 2);
    // staging: lane i -> row i/4, swizzled global seg; LDS dst = base + lane*16
    int srow0 = wave * 32 + (lane >> 2);
    int srow1 = srow0 + 16;
    int sseg = ((lane & 3) ^ ((lane >> 3) & 3)) * 8;   // shorts
    int rmA0 = m0 + srow0; if (rmA0 >= M) rmA0 = M - 1;   // clamp: rows>=M never stored
    int rmA1 = m0 + srow1; if (rmA1 >= M) rmA1 = M - 1;
    const unsigned short* gA0 = A + (size_t)rmA0 * K + sseg;
    const unsigned short* gA1 = A + (size_t)rmA1 * K + sseg;
    int browB = (BN == 128) ? srow0 : (wave * 16 + (lane >> 2));
    const unsigned short* gB0 = Bt + (size_t)(n0 + browB) * K + sseg;
    const unsigned short* gB1 = Bt + (size_t)(n0 + srow1) * K + sseg;  // BN=128 only
    int lofsA = wave * 1024 + lane * 8;
    int lofsB = ((BN == 128) ? wave * 1024 : wave * 512) + lane * 8;
    f32x4 acc[4][NI] = {};
    // prologue: stage tile 0 into buf 0
    gl2lds16(gA0, &As[0][lofsA]);
    gl2lds16(gA1, &As[0][lofsA + 512]);
    gl2lds16(gB0, &Bs[0][lofsB]);
    if (BN == 128) gl2lds16(gB1, &Bs[0][lofsB + 512]);
    int cur = 0;
    for (int k0 = 0; k0 < K; k0 += 32) {
        __syncthreads();                     // drain loads for buf cur
        int kn = k0 + 32;
        if (kn < K) {                        // prefetch next tile into buf cur^1
            gl2lds16(gA0 + kn, &As[cur ^ 1][lofsA]);
            gl2lds16(gA1 + kn, &As[cur ^ 1][lofsA + 512]);
            gl2lds16(gB0 + kn, &Bs[cur ^ 1][lofsB]);
            if (BN == 128) gl2lds16(gB1 + kn, &Bs[cur ^ 1][lofsB + 512]);
        }
        bf16x8 bfr[NI];
        #pragma unroll
        for (int ni = 0; ni < NI; ni++)
            bfr[ni] = *(bf16x8*)&Bs[cur][(wn + ni * 16 + l15) * 32 + xq8];
        #pragma unroll
        for (int mi = 0; mi < 4; mi++) {
            bf16x8 afr = *(bf16x8*)&As[cur][(wm + mi * 16 + l15) * 32 + xq8];
            #pragma unroll
            for (int ni = 0; ni < NI; ni++)
                acc[mi][ni] = __builtin_amdgcn_mfma_f32_16x16x32_bf16(
                    afr, bfr[ni], acc[mi][ni], 0, 0, 0);
        }
        cur ^= 1;
    }
    int q4r = (lane >> 4) * 4;
    #pragma unroll
    for (int mi = 0; mi < 4; mi++) {
        #pragma unroll
        for (int r = 0; r < 4; r++) {
            int row = m0 + wm + mi * 16 + q4r + r;
            if (row >= M) continue;
            if (EPI == 2) {
                int w = row / NTOK, t = row % NTOK;
                int bi = w / 25, wr = w % 25;
                int gy = (wr / 5) * WIN + t / WIN;
                int gx = (wr % 5) * WIN + t % WIN;
                if (gy >= 64 || gx >= 64) continue;
                size_t orow = ((size_t)((bi * 64 + gy) * 64 + gx)) * DIMC;
                #pragma unroll
                for (int ni = 0; ni < NI; ni++) {
                    int col = n0 + wn + ni * 16 + l15;
                    float v = acc[mi][ni][r] + bias[col];
                    ((float*)Cout)[orow + col] = resid[orow + col] + v;
                }
            } else {
                #pragma unroll
                for (int ni = 0; ni < NI; ni++) {
                    int col = n0 + wn + ni * 16 + l15;
                    float v = acc[mi][ni][r] + bias[col];
                    if (EPI == 0) {
                        ((unsigned short*)Cout)[(size_t)row * Nn + col] = f2bf(v);
                    } else if (EPI == 1) {
                        v = 0.5f * v * (1.f + erff(v * 0.70710678118654752f));
                        ((unsigned short*)Cout)[(size_t)row * Nn + col] = f2bf(v);
                    } else {
                        ((float*)Cout)[(size_t)row * Nn + col] =
                            resid[(size_t)row * Nn + col] + v;
                    }
                }
            }
        }
    }
}

// ---------------------------------------------------------------------------
extern "C" void kernel_launch(void* const* d_in, const int* in_sizes, int n_in,
                              void* d_out, int out_size, void* d_ws, size_t ws_size,
                              hipStream_t stream) {
    const float* x      = (const float*)d_in[0];
    const float* ln1_g  = (const float*)d_in[1];
    const float* ln1_b  = (const float*)d_in[2];
    const float* qkv_w  = (const float*)d_in[3];
    const float* qkv_b  = (const float*)d_in[4];
    const float* proj_w = (const float*)d_in[5];
    const float* proj_b = (const float*)d_in[6];
    const float* rel_h  = (const float*)d_in[7];
    const float* rel_w  = (const float*)d_in[8];
    const float* ln2_g  = (const float*)d_in[9];
    const float* ln2_b  = (const float*)d_in[10];
    const float* fc1_w  = (const float*)d_in[11];
    const float* fc1_b  = (const float*)d_in[12];
    const float* fc2_w  = (const float*)d_in[13];
    const float* fc2_b  = (const float*)d_in[14];
    float* out = (float*)d_out;
    char* ws = (char*)d_ws;

    // Workspace regions (max 121,061,376 B), liveness-checked (same as R3-R7):
    unsigned short* wt_qkv  = (unsigned short*)(ws);
    unsigned short* wt_proj = (unsigned short*)(ws + 3538944);
    unsigned short* wt_fc1  = (unsigned short*)(ws + 4718592);
    unsigned short* wt_fc2  = (unsigned short*)(ws + 9437184);
    unsigned short* qkvb    = (unsigned short*)(ws + 14155776);
    float*          yb      = (float*)        (ws + 14155776);
    unsigned short* h2      = (unsigned short*)(ws + 39321600);
    unsigned short* h1      = (unsigned short*)(ws + 59314176);
    unsigned short* attn_o  = h1;
    unsigned short* zb      = h1;
    unsigned short* Aaug    = (unsigned short*)(ws + 74366976);
    unsigned short* Vt      = (unsigned short*)(ws + 103858176);

    transpose_all<<<1728, 256, 0, stream>>>(
        qkv_w, wt_qkv, proj_w, wt_proj, fc1_w, wt_fc1, fc2_w, wt_fc2);

    ln1_win_kernel<<<(MROWS + 3) / 4, 256, 0, stream>>>(x, ln1_g, ln1_b, h1);

    mgemm<0, 128><<<18 * 77, 256, 0, stream>>>(
        h1, wt_qkv, qkv_b, qkvb, nullptr, MROWS, 2304, DIMC, 18, 77);

    build_aug<<<NWIN * HEADS, 256, 0, stream>>>(qkvb, rel_h, rel_w, Aaug, Vt);

    attn_mfma<<<NWIN * HEADS, 256, 0, stream>>>(qkvb, Aaug, Vt, attn_o);

    mgemm<2, 64><<<12 * 77, 256, 0, stream>>>(
        attn_o, wt_proj, proj_b, yb, x, MROWS, DIMC, DIMC, 12, 77);

    ln2_kernel<<<YROWS / 4, 256, 0, stream>>>(yb, ln2_g, ln2_b, h2);

    mgemm<1, 128><<<24 * 64, 256, 0, stream>>>(
        h2, wt_fc1, fc1_b, zb, nullptr, YROWS, MLP_HID, DIMC, 24, 64);

    mgemm<3, 64><<<12 * 64, 256, 0, stream>>>(
        zb, wt_fc2, fc2_b, out, yb, YROWS, DIMC, MLP_HID, 12, 64);
}